// Round 12
// baseline (1476.583 us; speedup 1.0000x reference)
//
#include <hip/hip_runtime.h>
#include <cstdint>

#define FDIM 128
#define PCH 64

static inline int cdiv(long long a, long long b) { return (int)((a + b - 1) / b); }

// ---------------- degree histograms (standalone fallback) ----------------
__global__ __launch_bounds__(256) void degi_kernel(const int* __restrict__ src,
                                                   const int* __restrict__ dst,
                                                   int* __restrict__ deg_in,
                                                   int* __restrict__ deg_out, int E) {
  int base = (blockIdx.x * 256 + threadIdx.x) * 2;
  if (base + 2 <= E) {
    int2 s2 = *(const int2*)(src + base);
    int2 d2 = *(const int2*)(dst + base);
    atomicAdd(&deg_in[d2.x], 1);
    atomicAdd(&deg_in[d2.y], 1);
    atomicAdd(&deg_out[s2.x], 1);
    atomicAdd(&deg_out[s2.y], 1);
  } else {
    for (int i = base; i < E; i++) {
      atomicAdd(&deg_in[dst[i]], 1);
      atomicAdd(&deg_out[src[i]], 1);
    }
  }
}

__global__ __launch_bounds__(256) void dinv2_kernel(const int* __restrict__ degs,
                                                    float* __restrict__ dinv, int n2) {
  int i = blockIdx.x * 256 + threadIdx.x;
  if (i < n2) {
    int v = degs[i];
    dinv[i] = v > 0 ? 1.0f / sqrtf((float)v) : 0.f;
  }
}

// batch is sorted: cnt[g] = upper_bound(g) - lower_bound(g). No atomics.
__global__ __launch_bounds__(256) void cnt_sorted(const int* __restrict__ batch,
                                                  float* __restrict__ cnt, int N, int G) {
  int g = blockIdx.x * 256 + threadIdx.x;
  if (g >= G) return;
  int lo = 0, hi = N;
  while (lo < hi) { int mid = (lo + hi) >> 1; if (batch[mid] < g) lo = mid + 1; else hi = mid; }
  int lo2 = lo, hi2 = N;
  while (lo2 < hi2) { int mid = (lo2 + hi2) >> 1; if (batch[mid] <= g) lo2 = mid + 1; else hi2 = mid; }
  cnt[g] = (float)(lo2 - lo);
}

// ---------------- hierarchical exclusive scan over concatenated [deg_in|deg_out] ----------------
__global__ __launch_bounds__(256) void scan1(const int* __restrict__ in, int* __restrict__ out,
                                             int* __restrict__ bsums, int n) {
  __shared__ int tmp[256];
  int t = threadIdx.x;
  int base = blockIdx.x * 1024 + t * 4;
  int a[4];
#pragma unroll
  for (int j = 0; j < 4; j++) a[j] = (base + j < n) ? in[base + j] : 0;
  int s = a[0] + a[1] + a[2] + a[3];
  tmp[t] = s;
  __syncthreads();
  for (int off = 1; off < 256; off <<= 1) {
    int v = (t >= off) ? tmp[t - off] : 0;
    __syncthreads();
    tmp[t] += v;
    __syncthreads();
  }
  int excl = tmp[t] - s;
  int run = excl;
#pragma unroll
  for (int j = 0; j < 4; j++) {
    if (base + j < n) out[base + j] = run;
    run += a[j];
  }
  if (t == 255) bsums[blockIdx.x] = tmp[255];
}

__global__ __launch_bounds__(256) void scan2(const int* __restrict__ bsums,
                                             int* __restrict__ boff, int nb) {
  __shared__ int tmp[256];
  int t = threadIdx.x;
  int s = (t < nb) ? bsums[t] : 0;
  tmp[t] = s;
  __syncthreads();
  for (int off = 1; off < 256; off <<= 1) {
    int v = (t >= off) ? tmp[t - off] : 0;
    __syncthreads();
    tmp[t] += v;
    __syncthreads();
  }
  if (t < nb) boff[t] = tmp[t] - s;
}

__global__ __launch_bounds__(256) void scan3(const int* __restrict__ scanned,
                                             const int* __restrict__ boff,
                                             int* __restrict__ rp_in, int* __restrict__ cur_in,
                                             int* __restrict__ rp_out, int* __restrict__ cur_out,
                                             int N, int E, int n2) {
  int i = blockIdx.x * 256 + threadIdx.x;
  if (i < n2) {
    int v = scanned[i] + boff[i >> 10];
    if (i < N) { rp_in[i] = v; cur_in[i] = v; }
    else { v -= E; rp_out[i - N] = v; cur_out[i - N] = v; }
  }
}

// ================= shared device helpers =================

__device__ __forceinline__ float4 gcn_node_val(int d, int lane,
    const float4* __restrict__ tin, const float4* __restrict__ tout,
    const int* __restrict__ rp_in, const int* __restrict__ deg_in, const int2* __restrict__ adj_in,
    const int* __restrict__ rp_out, const int* __restrict__ deg_out, const int* __restrict__ adj_out,
    const float* __restrict__ dinv_in, const float* __restrict__ dinv_out,
    const float* __restrict__ bin, const float* __restrict__ bout) {
  float wi = 0.5f * dinv_in[d], wo = 0.5f * dinv_out[d];
  float4 a0 = make_float4(0.f, 0.f, 0.f, 0.f);
  float4 a1 = a0, a2 = a0, a3 = a0;

  int p = rp_in[d], n1 = deg_in[d];
  int k = 0;
  for (; k + 4 <= n1; k += 4) {
    int s0 = adj_in[p + k].x, s1 = adj_in[p + k + 1].x, s2 = adj_in[p + k + 2].x, s3 = adj_in[p + k + 3].x;
    float w0 = wi * dinv_in[s0], w1 = wi * dinv_in[s1], w2 = wi * dinv_in[s2], w3 = wi * dinv_in[s3];
    float4 v0 = tin[(size_t)s0 * 32 + lane];
    float4 v1 = tin[(size_t)s1 * 32 + lane];
    float4 v2 = tin[(size_t)s2 * 32 + lane];
    float4 v3 = tin[(size_t)s3 * 32 + lane];
    a0.x += w0 * v0.x; a0.y += w0 * v0.y; a0.z += w0 * v0.z; a0.w += w0 * v0.w;
    a1.x += w1 * v1.x; a1.y += w1 * v1.y; a1.z += w1 * v1.z; a1.w += w1 * v1.w;
    a2.x += w2 * v2.x; a2.y += w2 * v2.y; a2.z += w2 * v2.z; a2.w += w2 * v2.w;
    a3.x += w3 * v3.x; a3.y += w3 * v3.y; a3.z += w3 * v3.z; a3.w += w3 * v3.w;
  }
  for (; k < n1; k++) {
    int s = adj_in[p + k].x;
    float w = wi * dinv_in[s];
    float4 v = tin[(size_t)s * 32 + lane];
    a0.x += w * v.x; a0.y += w * v.y; a0.z += w * v.z; a0.w += w * v.w;
  }

  int q = rp_out[d], n2 = deg_out[d];
  k = 0;
  for (; k + 4 <= n2; k += 4) {
    int s0 = adj_out[q + k], s1 = adj_out[q + k + 1], s2 = adj_out[q + k + 2], s3 = adj_out[q + k + 3];
    float w0 = wo * dinv_out[s0], w1 = wo * dinv_out[s1], w2 = wo * dinv_out[s2], w3 = wo * dinv_out[s3];
    float4 v0 = tout[(size_t)s0 * 32 + lane];
    float4 v1 = tout[(size_t)s1 * 32 + lane];
    float4 v2 = tout[(size_t)s2 * 32 + lane];
    float4 v3 = tout[(size_t)s3 * 32 + lane];
    a0.x += w0 * v0.x; a0.y += w0 * v0.y; a0.z += w0 * v0.z; a0.w += w0 * v0.w;
    a1.x += w1 * v1.x; a1.y += w1 * v1.y; a1.z += w1 * v1.z; a1.w += w1 * v1.w;
    a2.x += w2 * v2.x; a2.y += w2 * v2.y; a2.z += w2 * v2.z; a2.w += w2 * v2.w;
    a3.x += w3 * v3.x; a3.y += w3 * v3.y; a3.z += w3 * v3.z; a3.w += w3 * v3.w;
  }
  for (; k < n2; k++) {
    int s = adj_out[q + k];
    float w = wo * dinv_out[s];
    float4 v = tout[(size_t)s * 32 + lane];
    a0.x += w * v.x; a0.y += w * v.y; a0.z += w * v.z; a0.w += w * v.w;
  }

  float4 acc;
  acc.x = (a0.x + a1.x) + (a2.x + a3.x);
  acc.y = (a0.y + a1.y) + (a2.y + a3.y);
  acc.z = (a0.z + a1.z) + (a2.z + a3.z);
  acc.w = (a0.w + a1.w) + (a2.w + a3.w);

  float4 ba = ((const float4*)bin)[lane], bb = ((const float4*)bout)[lane];
  float4 o;
  o.x = acc.x + 0.5f * (ba.x + bb.x);
  o.y = acc.y + 0.5f * (ba.y + bb.y);
  o.z = acc.z + 0.5f * (ba.z + bb.z);
  o.w = acc.w + 0.5f * (ba.w + bb.w);
  o.x = o.x > 0.f ? o.x : 0.f;
  o.y = o.y > 0.f ? o.y : 0.f;
  o.z = o.z > 0.f ? o.z : 0.f;
  o.w = o.w > 0.f ? o.w : 0.f;
  return o;
}

__device__ __forceinline__ float4 gat_node_val(int d, int lane,
    const float4* __restrict__ gl, const float4* __restrict__ gr,
    const int* __restrict__ rp, const int* __restrict__ deg, const int2* __restrict__ adj,
    const float* __restrict__ we, const float* __restrict__ att,
    const float* __restrict__ gatb) {
  float4 grv = gr[(size_t)d * 32 + lane];
  float4 wev = ((const float4*)we)[lane];
  float4 atv = ((const float4*)att)[lane];

  int p = rp[d], n1 = deg[d];
  float m = -1e30f, den = 0.f;
  float4 o = make_float4(0.f, 0.f, 0.f, 0.f);

#define GAT_LOGIT(g4, ea, pv)                                                     \
  {                                                                               \
    float vx = g4.x + grv.x + (ea) * wev.x; vx = vx > 0.f ? vx : 0.2f * vx;       \
    float vy = g4.y + grv.y + (ea) * wev.y; vy = vy > 0.f ? vy : 0.2f * vy;       \
    float vz = g4.z + grv.z + (ea) * wev.z; vz = vz > 0.f ? vz : 0.2f * vz;       \
    float vw = g4.w + grv.w + (ea) * wev.w; vw = vw > 0.f ? vw : 0.2f * vw;       \
    pv = vx * atv.x + vy * atv.y + vz * atv.z + vw * atv.w;                       \
    pv += __shfl_xor(pv, 1);                                                      \
    pv += __shfl_xor(pv, 2);                                                      \
    pv += __shfl_xor(pv, 4);                                                      \
  }

#define GAT_UPDATE(g4, pv)                                                        \
  {                                                                               \
    float mn = fmaxf(m, pv);                                                      \
    float sc = expf(m - mn);                                                      \
    float w = expf(pv - mn);                                                      \
    den = den * sc + w;                                                           \
    o.x = o.x * sc + w * g4.x;                                                    \
    o.y = o.y * sc + w * g4.y;                                                    \
    o.z = o.z * sc + w * g4.z;                                                    \
    o.w = o.w * sc + w * g4.w;                                                    \
    m = mn;                                                                       \
  }

  int k = 0;
  for (; k + 2 <= n1; k += 2) {
    int2 e0 = adj[p + k], e1 = adj[p + k + 1];
    float ea0 = __int_as_float(e0.y), ea1 = __int_as_float(e1.y);
    float4 g0 = gl[(size_t)e0.x * 32 + lane];
    float4 g1 = gl[(size_t)e1.x * 32 + lane];
    float pv0, pv1;
    GAT_LOGIT(g0, ea0, pv0);
    GAT_LOGIT(g1, ea1, pv1);
    GAT_UPDATE(g0, pv0);
    GAT_UPDATE(g1, pv1);
  }
  if (k < n1) {
    int2 e = adj[p + k];
    float ea = __int_as_float(e.y);
    float4 g = gl[(size_t)e.x * 32 + lane];
    float pv;
    GAT_LOGIT(g, ea, pv);
    GAT_UPDATE(g, pv);
  }
  {  // self loop: s = d, ea = 1.0
    float4 g = gl[(size_t)d * 32 + lane];
    float pv;
    GAT_LOGIT(g, 1.0f, pv);
    GAT_UPDATE(g, pv);
  }
#undef GAT_LOGIT
#undef GAT_UPDATE

  float4 bb = ((const float4*)gatb)[lane];
  float4 r;
  r.x = o.x / den + bb.x;
  r.y = o.y / den + bb.y;
  r.z = o.z / den + bb.z;
  r.w = o.w / den + bb.w;
  return r;
}

// dual matmul role body: 64-row tile, out0=A@W0 out1=A@W1 (As 32K + Ws 16K LDS)
__device__ __forceinline__ void mm64_dual(const float* __restrict__ A,
                                          const float* __restrict__ W0,
                                          const float* __restrict__ W1,
                                          float* __restrict__ out0,
                                          float* __restrict__ out1,
                                          int nrows, int r0, int tid,
                                          float (*As)[128], float (*Ws)[64]) {
#pragma unroll
  for (int i = 0; i < 8; i++) {
    int v = tid + 256 * i;
    int r = v >> 5, k4 = (v & 31) << 2;
    int row = r0 + r;
    float4 a;
    if (row < nrows) a = *(const float4*)(A + (size_t)row * FDIM + k4);
    else a = make_float4(0.f, 0.f, 0.f, 0.f);
    int swz = ((r >> 2) & 7) << 2;
    *(float4*)(&As[r][k4 ^ swz]) = a;
  }

  int tx = tid & 15, ty = tid >> 4;
  int rbase = ty * 4;
  int swz = (ty & 7) << 2;

  for (int p = 0; p < 4; p++) {
    const float* W = (p < 2) ? W0 : W1;
    float* out = (p < 2) ? out0 : out1;
    int cb = (p & 1) * 64;
    float acc[4][4] = {};

    for (int kh = 0; kh < 2; kh++) {
      __syncthreads();
#pragma unroll
      for (int i = 0; i < 4; i++) {
        int v = tid + 256 * i;
        int k = v >> 4, c4 = (v & 15) << 2;
        *(float4*)(&Ws[k][c4]) = *(const float4*)(W + (kh * 64 + k) * FDIM + cb + c4);
      }
      __syncthreads();

#pragma unroll 8
      for (int k = 0; k < 64; k++) {
        int kx = (kh * 64 + k) ^ swz;
        float a0 = As[rbase + 0][kx];
        float a1 = As[rbase + 1][kx];
        float a2 = As[rbase + 2][kx];
        float a3 = As[rbase + 3][kx];
        float4 w = *(float4*)(&Ws[k][tx * 4]);
        acc[0][0] += a0 * w.x; acc[0][1] += a0 * w.y; acc[0][2] += a0 * w.z; acc[0][3] += a0 * w.w;
        acc[1][0] += a1 * w.x; acc[1][1] += a1 * w.y; acc[1][2] += a1 * w.z; acc[1][3] += a1 * w.w;
        acc[2][0] += a2 * w.x; acc[2][1] += a2 * w.y; acc[2][2] += a2 * w.z; acc[2][3] += a2 * w.w;
        acc[3][0] += a3 * w.x; acc[3][1] += a3 * w.y; acc[3][2] += a3 * w.z; acc[3][3] += a3 * w.w;
      }
    }

#pragma unroll
    for (int rr = 0; rr < 4; rr++) {
      int row = r0 + rbase + rr;
      if (row < nrows) {
        float4 o = make_float4(acc[rr][0], acc[rr][1], acc[rr][2], acc[rr][3]);
        *(float4*)(out + (size_t)row * FDIM + cb + tx * 4) = o;
      }
    }
  }
}

// ================= fused heterogeneous kernels =================

// mmgat_degi: dual mm (x@wl->B, x@wr->C) || degree histogram
__global__ __launch_bounds__(256) void mmgat_degi(const float* __restrict__ x,
                                                  const float* __restrict__ wl,
                                                  const float* __restrict__ wr,
                                                  float* __restrict__ B,
                                                  float* __restrict__ C, int N, int mmB,
                                                  const int* __restrict__ src,
                                                  const int* __restrict__ dst,
                                                  int* __restrict__ deg_in,
                                                  int* __restrict__ deg_out, int E, int degB) {
  __shared__ float As[64][128];
  __shared__ float Ws[64][64];
  int T = mmB + degB;
  int bid = blockIdx.x, tid = threadIdx.x;
  long long f0 = (long long)bid * degB / T;
  long long f1 = (long long)(bid + 1) * degB / T;
  if (f1 > f0) {
    int base = ((int)f0 * 256 + tid) * 2;
    if (base + 2 <= E) {
      int2 s2 = *(const int2*)(src + base);
      int2 d2 = *(const int2*)(dst + base);
      atomicAdd(&deg_in[d2.x], 1);
      atomicAdd(&deg_in[d2.y], 1);
      atomicAdd(&deg_out[s2.x], 1);
      atomicAdd(&deg_out[s2.y], 1);
    } else {
      for (int i = base; i < E; i++) {
        atomicAdd(&deg_in[dst[i]], 1);
        atomicAdd(&deg_out[src[i]], 1);
      }
    }
    return;
  }
  int mb = bid - (int)f0;
  mm64_dual(x, wl, wr, B, C, N, mb * 64, tid, As, Ws);
}

// mm0_fill: dual mm (x@dwi->A, x@dwo->D) || CSR fill
__global__ __launch_bounds__(256) void mm0_fill(const float* __restrict__ x,
                                                const float* __restrict__ W0,
                                                const float* __restrict__ W1,
                                                float* __restrict__ out0,
                                                float* __restrict__ out1, int nrows, int mmB,
                                                const int* __restrict__ src,
                                                const int* __restrict__ dst,
                                                const float* __restrict__ eattr,
                                                int* __restrict__ cur_in,
                                                int* __restrict__ cur_out,
                                                int2* __restrict__ csr_in,
                                                int* __restrict__ csr_out_dst, int E, int fillB) {
  __shared__ float As[64][128];
  __shared__ float Ws[64][64];
  int T = mmB + fillB;
  int bid = blockIdx.x;
  int tid = threadIdx.x;
  long long f0 = (long long)bid * fillB / T;
  long long f1 = (long long)(bid + 1) * fillB / T;

  if (f1 > f0) {
    int base = ((int)f0 * 256 + tid) * 4;
    if (base + 4 <= E) {
      int4 s4 = *(const int4*)(src + base);
      int4 d4 = *(const int4*)(dst + base);
      float4 e4 = *(const float4*)(eattr + base);
      int p0 = atomicAdd(&cur_in[d4.x], 1);
      int p1 = atomicAdd(&cur_in[d4.y], 1);
      int p2 = atomicAdd(&cur_in[d4.z], 1);
      int p3 = atomicAdd(&cur_in[d4.w], 1);
      int q0 = atomicAdd(&cur_out[s4.x], 1);
      int q1 = atomicAdd(&cur_out[s4.y], 1);
      int q2 = atomicAdd(&cur_out[s4.z], 1);
      int q3 = atomicAdd(&cur_out[s4.w], 1);
      csr_in[p0] = make_int2(s4.x, __float_as_int(e4.x));
      csr_in[p1] = make_int2(s4.y, __float_as_int(e4.y));
      csr_in[p2] = make_int2(s4.z, __float_as_int(e4.z));
      csr_in[p3] = make_int2(s4.w, __float_as_int(e4.w));
      csr_out_dst[q0] = d4.x;
      csr_out_dst[q1] = d4.y;
      csr_out_dst[q2] = d4.z;
      csr_out_dst[q3] = d4.w;
    } else {
      for (int i = base; i < E; i++) {
        int s = src[i], d = dst[i];
        int p = atomicAdd(&cur_in[d], 1);
        csr_in[p] = make_int2(s, __float_as_int(eattr[i]));
        int q = atomicAdd(&cur_out[s], 1);
        csr_out_dst[q] = d;
      }
    }
    return;
  }

  int mb = bid - (int)f0;
  mm64_dual(x, W0, W1, out0, out1, nrows, mb * 64, tid, As, Ws);
}

// GAT aggregation + mean-pool accumulation (gl,gr -> zb cols 128..255)
__global__ __launch_bounds__(128) void gat_pool(const float4* __restrict__ gl,
                                                const float4* __restrict__ gr,
                                                const int* __restrict__ rp,
                                                const int* __restrict__ deg,
                                                const int2* __restrict__ adj,
                                                const float* __restrict__ we,
                                                const float* __restrict__ att,
                                                const float* __restrict__ gatb,
                                                const int* __restrict__ batch,
                                                float* __restrict__ zb, int N) {
  int grp = threadIdx.x >> 5, lane = threadIdx.x & 31;
  int d = blockIdx.x * 4 + grp;
  if (d >= N) return;
  float4 r = gat_node_val(d, lane, gl, gr, rp, deg, adj, we, att, gatb);
  int g = batch[d];
  float* dstp = &zb[(size_t)g * 256 + 128 + lane * 4];
  atomicAdd(dstp + 0, r.x);
  atomicAdd(dstp + 1, r.y);
  atomicAdd(dstp + 2, r.z);
  atomicAdd(dstp + 3, r.w);
}

// GCN gather -> dense output (layer 0)
__global__ __launch_bounds__(128) void gcn_gather4(const float4* __restrict__ tin,
                                                   const float4* __restrict__ tout,
                                                   const int* __restrict__ rp_in,
                                                   const int* __restrict__ deg_in,
                                                   const int2* __restrict__ adj_in,
                                                   const int* __restrict__ rp_out,
                                                   const int* __restrict__ deg_out,
                                                   const int* __restrict__ adj_out,
                                                   const float* __restrict__ dinv_in,
                                                   const float* __restrict__ dinv_out,
                                                   const float* __restrict__ bin,
                                                   const float* __restrict__ bout,
                                                   float4* __restrict__ outp, int N) {
  int grp = threadIdx.x >> 5, lane = threadIdx.x & 31;
  int d = blockIdx.x * 4 + grp;
  if (d >= N) return;
  float4 o = gcn_node_val(d, lane, tin, tout, rp_in, deg_in, adj_in,
                          rp_out, deg_out, adj_out, dinv_in, dinv_out, bin, bout);
  outp[(size_t)d * 32 + lane] = o;
}

// GCN gather (layer 1) + mean-pool accumulation (-> zb cols 0..127)
__global__ __launch_bounds__(128) void gcn_gather_pool(
    const float4* __restrict__ tin, const float4* __restrict__ tout,
    const int* __restrict__ rp_in, const int* __restrict__ deg_in, const int2* __restrict__ adj_in,
    const int* __restrict__ rp_out, const int* __restrict__ deg_out, const int* __restrict__ adj_out,
    const float* __restrict__ dinv_in, const float* __restrict__ dinv_out,
    const float* __restrict__ bin, const float* __restrict__ bout,
    const int* __restrict__ batch, float* __restrict__ zb, int N) {
  int grp = threadIdx.x >> 5, lane = threadIdx.x & 31;
  int d = blockIdx.x * 4 + grp;
  if (d >= N) return;
  float4 o = gcn_node_val(d, lane, tin, tout, rp_in, deg_in, adj_in,
                          rp_out, deg_out, adj_out, dinv_in, dinv_out, bin, bout);
  int g = batch[d];
  float* dstp = &zb[(size_t)g * 256 + lane * 4];
  atomicAdd(dstp + 0, o.x);
  atomicAdd(dstp + 1, o.y);
  atomicAdd(dstp + 2, o.z);
  atomicAdd(dstp + 3, o.w);
}

// standalone dual matmul
__global__ __launch_bounds__(256) void mm128d(const float* __restrict__ A,
                                              const float* __restrict__ W0,
                                              const float* __restrict__ W1,
                                              float* __restrict__ out0,
                                              float* __restrict__ out1, int nrows) {
  __shared__ float As[64][128];
  __shared__ float Ws[64][64];
  mm64_dual(A, W0, W1, out0, out1, nrows, blockIdx.x * 64, threadIdx.x, As, Ws);
}

// GAT -> dense output (fallback)
__global__ __launch_bounds__(128) void gat_fused2(const float4* __restrict__ gl,
                                                  const float4* __restrict__ gr,
                                                  const int* __restrict__ rp,
                                                  const int* __restrict__ deg,
                                                  const int2* __restrict__ adj,
                                                  const float* __restrict__ we,
                                                  const float* __restrict__ att,
                                                  const float* __restrict__ gatb,
                                                  float4* __restrict__ outp, int N) {
  int grp = threadIdx.x >> 5, lane = threadIdx.x & 31;
  int d = blockIdx.x * 4 + grp;
  if (d >= N) return;
  float4 r = gat_node_val(d, lane, gl, gr, rp, deg, adj, we, att, gatb);
  outp[(size_t)d * 32 + lane] = r;
}

// mean pool over dense buffer (fallback)
__global__ __launch_bounds__(128) void pool_kernel(const float* __restrict__ srcf,
                                                   const int* __restrict__ batch,
                                                   float* __restrict__ zb,
                                                   int colOff, int N) {
  __shared__ int sb[PCH];
  int c0 = blockIdx.x * PCH;
  int t = threadIdx.x;
  int nmax = N - c0; if (nmax > PCH) nmax = PCH;
  if (t < nmax) sb[t] = batch[c0 + t];
  __syncthreads();
  float run = 0.f;
  int gp = sb[0];
  for (int i = 0; i < nmax; i++) {
    int g = sb[i];
    if (g != gp) {
      atomicAdd(&zb[(size_t)gp * 256 + colOff + t], run);
      run = 0.f; gp = g;
    }
    run += srcf[(size_t)(c0 + i) * FDIM + t];
  }
  atomicAdd(&zb[(size_t)gp * 256 + colOff + t], run);
}

// ---------------- head ----------------
__global__ __launch_bounds__(128) void head_kernel(const float* __restrict__ zb,
                                                   const float* __restrict__ cnt,
                                                   const float* __restrict__ w1,
                                                   const float* __restrict__ b1,
                                                   const float* __restrict__ w2,
                                                   const float* __restrict__ b2,
                                                   float* __restrict__ out, int G) {
  __shared__ float z[256];
  __shared__ float y[128];
  int g = blockIdx.x, t = threadIdx.x;
  float c = cnt[g];
  float cm = c > 1.f ? c : 1.f;
  z[t]       = zb[(size_t)g * 256 + t] / cm;
  z[t + 128] = zb[(size_t)g * 256 + 128 + t] / cm;
  __syncthreads();
  float acc = b1[t];
  for (int k = 0; k < 256; k++) acc += z[k] * w1[k * 128 + t];
  y[t] = acc > 0.f ? acc : 0.f;
  __syncthreads();
  if (t < 2) {
    float o = b2[t];
    for (int j = 0; j < 128; j++) o += y[j] * w2[j * 2 + t];
    out[(size_t)g * 2 + t] = o;
  }
}

extern "C" void kernel_launch(void* const* d_in, const int* in_sizes, int n_in,
                              void* d_out, int out_size, void* d_ws, size_t ws_size,
                              hipStream_t stream) {
  const float* x     = (const float*)d_in[0];
  const int*   ei    = (const int*)d_in[1];
  const float* eattr = (const float*)d_in[2];
  const int*   batch = (const int*)d_in[3];
  const float* dwi   = (const float*)d_in[4];
  const float* dbi   = (const float*)d_in[5];
  const float* dwo   = (const float*)d_in[6];
  const float* dbo   = (const float*)d_in[7];
  const float* wl    = (const float*)d_in[8];
  const float* wr    = (const float*)d_in[9];
  const float* we    = (const float*)d_in[10];
  const float* att   = (const float*)d_in[11];
  const float* gatb  = (const float*)d_in[12];
  const float* w1    = (const float*)d_in[13];
  const float* b1    = (const float*)d_in[14];
  const float* w2    = (const float*)d_in[15];
  const float* b2    = (const float*)d_in[16];

  int N = in_sizes[0] / FDIM;
  int E = in_sizes[1] / 2;
  int G = out_size / 2;
  const int* src = ei;
  const int* dst = ei + E;

  size_t nf = (size_t)N * FDIM;
  size_t fixed = 10 * (size_t)N + 3 * (size_t)E + 512 + (size_t)G * 257;
  bool main_path = ((4 * nf + fixed) * sizeof(float)) <= ws_size;
  int nbuf = main_path ? 4 : 3;

  float* ws = (float*)d_ws;
  size_t off = 0;
  float* A = ws + off; off += nf;
  float* B = ws + off; off += nf;
  float* C = ws + off; off += nf;
  float* D = nullptr;
  if (nbuf == 4) { D = ws + off; off += nf; }
  float* dinv2    = ws + off; off += 2 * (size_t)N;
  int* deg2       = (int*)(ws + off); off += 2 * (size_t)N;
  int* rpt        = (int*)(ws + off); off += 2 * (size_t)N;
  int* rp_in      = (int*)(ws + off); off += (size_t)N;
  int* rp_out     = (int*)(ws + off); off += (size_t)N;
  int* cur_in     = (int*)(ws + off); off += (size_t)N;
  int* cur_out    = (int*)(ws + off); off += (size_t)N;
  int2* csr_in    = (int2*)(ws + off); off += 2 * (size_t)E;
  int* csr_out_dst= (int*)(ws + off); off += (size_t)E;
  int* bsums      = (int*)(ws + off); off += 256;
  int* boff       = (int*)(ws + off); off += 256;
  float* zb       = ws + off; off += (size_t)G * 256;
  float* cnt      = ws + off; off += (size_t)G;

  int* deg_in = deg2, *deg_out = deg2 + N;
  float* dinv_in = dinv2, *dinv_out = dinv2 + N;

  int n2 = 2 * N;
  int nb1 = cdiv(n2, 1024);
  int mmB = cdiv(N, 64);
  int fillB = cdiv(E, 1024);
  int degB = cdiv(E, 512);

  hipMemsetAsync(deg2, 0, (size_t)n2 * sizeof(int), stream);
  hipMemsetAsync(zb, 0, (size_t)G * 256 * sizeof(float), stream);

  if (main_path) {
    // S1: GAT transforms (x@wl->B, x@wr->C) || degree histogram
    mmgat_degi<<<mmB + degB, 256, 0, stream>>>(x, wl, wr, B, C, N, mmB,
                                               src, dst, deg_in, deg_out, E, degB);
    // S2: scans + counts
    dinv2_kernel<<<cdiv((long long)n2, 256), 256, 0, stream>>>(deg2, dinv2, n2);
    scan1<<<nb1, 256, 0, stream>>>(deg2, rpt, bsums, n2);
    scan2<<<1, 256, 0, stream>>>(bsums, boff, nb1);
    scan3<<<cdiv(n2, 256), 256, 0, stream>>>(rpt, boff, rp_in, cur_in, rp_out, cur_out, N, E, n2);
    cnt_sorted<<<cdiv(G, 256), 256, 0, stream>>>(batch, cnt, N, G);
    // S3: layer-0 transforms (x@dwi->A, x@dwo->D) || CSR fill
    mm0_fill<<<mmB + fillB, 256, 0, stream>>>(x, dwi, dwo, A, D, N, mmB,
                                              src, dst, eattr, cur_in, cur_out,
                                              csr_in, csr_out_dst, E, fillB);
    // S4: GAT aggregation + pool (B,C -> zb[:,128:])
    gat_pool<<<cdiv(N, 4), 128, 0, stream>>>((const float4*)B, (const float4*)C,
                                             rp_in, deg_in, csr_in,
                                             we, att, gatb, batch, zb, N);
    // S5: gather0 (A,D -> B)
    gcn_gather4<<<cdiv(N, 4), 128, 0, stream>>>((const float4*)A, (const float4*)D,
                                                rp_in, deg_in, csr_in,
                                                rp_out, deg_out, csr_out_dst,
                                                dinv_in, dinv_out, dbi, dbo, (float4*)B, N);
    // S6: layer-1 transforms (B@dwi1->C, B@dwo1->D)
    mm128d<<<mmB, 256, 0, stream>>>(B, dwi + 16384, dwo + 16384, C, D, N);
    // S7: gather1 + pool (C,D -> zb[:,0:128])
    gcn_gather_pool<<<cdiv(N, 4), 128, 0, stream>>>((const float4*)C, (const float4*)D,
                                                    rp_in, deg_in, csr_in,
                                                    rp_out, deg_out, csr_out_dst,
                                                    dinv_in, dinv_out, dbi + 128, dbo + 128,
                                                    batch, zb, N);
  } else {
    // fallback: R9 schedule (3 buffers)
    degi_kernel<<<degB, 256, 0, stream>>>(src, dst, deg_in, deg_out, E);
    dinv2_kernel<<<cdiv((long long)n2, 256), 256, 0, stream>>>(deg2, dinv2, n2);
    scan1<<<nb1, 256, 0, stream>>>(deg2, rpt, bsums, n2);
    scan2<<<1, 256, 0, stream>>>(bsums, boff, nb1);
    scan3<<<cdiv(n2, 256), 256, 0, stream>>>(rpt, boff, rp_in, cur_in, rp_out, cur_out, N, E, n2);
    cnt_sorted<<<cdiv(G, 256), 256, 0, stream>>>(batch, cnt, N, G);
    mm0_fill<<<mmB + fillB, 256, 0, stream>>>(x, dwi, dwo, B, C, N, mmB,
                                              src, dst, eattr, cur_in, cur_out,
                                              csr_in, csr_out_dst, E, fillB);
    gcn_gather4<<<cdiv(N, 4), 128, 0, stream>>>((const float4*)B, (const float4*)C,
                                                rp_in, deg_in, csr_in,
                                                rp_out, deg_out, csr_out_dst,
                                                dinv_in, dinv_out, dbi, dbo, (float4*)A, N);
    mm128d<<<mmB, 256, 0, stream>>>(A, dwi + 16384, dwo + 16384, B, C, N);
    gcn_gather_pool<<<cdiv(N, 4), 128, 0, stream>>>((const float4*)B, (const float4*)C,
                                                    rp_in, deg_in, csr_in,
                                                    rp_out, deg_out, csr_out_dst,
                                                    dinv_in, dinv_out, dbi + 128, dbo + 128,
                                                    batch, zb, N);
    mm128d<<<mmB, 256, 0, stream>>>(x, wl, wr, B, C, N);
    gat_pool<<<cdiv(N, 4), 128, 0, stream>>>((const float4*)B, (const float4*)C,
                                             rp_in, deg_in, csr_in,
                                             we, att, gatb, batch, zb, N);
  }

  // head
  head_kernel<<<G, 128, 0, stream>>>(zb, cnt, w1, b1, w2, b2, (float*)d_out, G);
}

// Round 13
// 1033.864 us; speedup vs baseline: 1.4282x; 1.4282x over previous
//
#include <hip/hip_runtime.h>
#include <cstdint>

#define FDIM 128
#define PCH 64

static inline int cdiv(long long a, long long b) { return (int)((a + b - 1) / b); }

// ---------------- degree histograms (standalone fallback) ----------------
__global__ __launch_bounds__(256) void degi_kernel(const int* __restrict__ src,
                                                   const int* __restrict__ dst,
                                                   int* __restrict__ deg_in,
                                                   int* __restrict__ deg_out, int E) {
  int base = (blockIdx.x * 256 + threadIdx.x) * 2;
  if (base + 2 <= E) {
    int2 s2 = *(const int2*)(src + base);
    int2 d2 = *(const int2*)(dst + base);
    atomicAdd(&deg_in[d2.x], 1);
    atomicAdd(&deg_in[d2.y], 1);
    atomicAdd(&deg_out[s2.x], 1);
    atomicAdd(&deg_out[s2.y], 1);
  } else {
    for (int i = base; i < E; i++) {
      atomicAdd(&deg_in[dst[i]], 1);
      atomicAdd(&deg_out[src[i]], 1);
    }
  }
}

__global__ __launch_bounds__(256) void dinv2_kernel(const int* __restrict__ degs,
                                                    float* __restrict__ dinv, int n2) {
  int i = blockIdx.x * 256 + threadIdx.x;
  if (i < n2) {
    int v = degs[i];
    dinv[i] = v > 0 ? 1.0f / sqrtf((float)v) : 0.f;
  }
}

// batch is sorted: cnt[g] = upper_bound(g) - lower_bound(g). No atomics.
__global__ __launch_bounds__(256) void cnt_sorted(const int* __restrict__ batch,
                                                  float* __restrict__ cnt, int N, int G) {
  int g = blockIdx.x * 256 + threadIdx.x;
  if (g >= G) return;
  int lo = 0, hi = N;
  while (lo < hi) { int mid = (lo + hi) >> 1; if (batch[mid] < g) lo = mid + 1; else hi = mid; }
  int lo2 = lo, hi2 = N;
  while (lo2 < hi2) { int mid = (lo2 + hi2) >> 1; if (batch[mid] <= g) lo2 = mid + 1; else hi2 = mid; }
  cnt[g] = (float)(lo2 - lo);
}

// ---------------- hierarchical exclusive scan over concatenated [deg_in|deg_out] ----------------
__global__ __launch_bounds__(256) void scan1(const int* __restrict__ in, int* __restrict__ out,
                                             int* __restrict__ bsums, int n) {
  __shared__ int tmp[256];
  int t = threadIdx.x;
  int base = blockIdx.x * 1024 + t * 4;
  int a[4];
#pragma unroll
  for (int j = 0; j < 4; j++) a[j] = (base + j < n) ? in[base + j] : 0;
  int s = a[0] + a[1] + a[2] + a[3];
  tmp[t] = s;
  __syncthreads();
  for (int off = 1; off < 256; off <<= 1) {
    int v = (t >= off) ? tmp[t - off] : 0;
    __syncthreads();
    tmp[t] += v;
    __syncthreads();
  }
  int excl = tmp[t] - s;
  int run = excl;
#pragma unroll
  for (int j = 0; j < 4; j++) {
    if (base + j < n) out[base + j] = run;
    run += a[j];
  }
  if (t == 255) bsums[blockIdx.x] = tmp[255];
}

__global__ __launch_bounds__(256) void scan2(const int* __restrict__ bsums,
                                             int* __restrict__ boff, int nb) {
  __shared__ int tmp[256];
  int t = threadIdx.x;
  int s = (t < nb) ? bsums[t] : 0;
  tmp[t] = s;
  __syncthreads();
  for (int off = 1; off < 256; off <<= 1) {
    int v = (t >= off) ? tmp[t - off] : 0;
    __syncthreads();
    tmp[t] += v;
    __syncthreads();
  }
  if (t < nb) boff[t] = tmp[t] - s;
}

__global__ __launch_bounds__(256) void scan3(const int* __restrict__ scanned,
                                             const int* __restrict__ boff,
                                             int* __restrict__ rp_in, int* __restrict__ cur_in,
                                             int* __restrict__ rp_out, int* __restrict__ cur_out,
                                             int N, int E, int n2) {
  int i = blockIdx.x * 256 + threadIdx.x;
  if (i < n2) {
    int v = scanned[i] + boff[i >> 10];
    if (i < N) { rp_in[i] = v; cur_in[i] = v; }
    else { v -= E; rp_out[i - N] = v; cur_out[i - N] = v; }
  }
}

// ================= shared device helpers =================

__device__ __forceinline__ float4 gcn_node_val(int d, int lane,
    const float4* __restrict__ tin, const float4* __restrict__ tout,
    const int* __restrict__ rp_in, const int* __restrict__ deg_in, const int2* __restrict__ adj_in,
    const int* __restrict__ rp_out, const int* __restrict__ deg_out, const int* __restrict__ adj_out,
    const float* __restrict__ dinv_in, const float* __restrict__ dinv_out,
    const float* __restrict__ bin, const float* __restrict__ bout) {
  float wi = 0.5f * dinv_in[d], wo = 0.5f * dinv_out[d];
  float4 a0 = make_float4(0.f, 0.f, 0.f, 0.f);
  float4 a1 = a0, a2 = a0, a3 = a0;

  int p = rp_in[d], n1 = deg_in[d];
  int k = 0;
  for (; k + 4 <= n1; k += 4) {
    int s0 = adj_in[p + k].x, s1 = adj_in[p + k + 1].x, s2 = adj_in[p + k + 2].x, s3 = adj_in[p + k + 3].x;
    float w0 = wi * dinv_in[s0], w1 = wi * dinv_in[s1], w2 = wi * dinv_in[s2], w3 = wi * dinv_in[s3];
    float4 v0 = tin[(size_t)s0 * 32 + lane];
    float4 v1 = tin[(size_t)s1 * 32 + lane];
    float4 v2 = tin[(size_t)s2 * 32 + lane];
    float4 v3 = tin[(size_t)s3 * 32 + lane];
    a0.x += w0 * v0.x; a0.y += w0 * v0.y; a0.z += w0 * v0.z; a0.w += w0 * v0.w;
    a1.x += w1 * v1.x; a1.y += w1 * v1.y; a1.z += w1 * v1.z; a1.w += w1 * v1.w;
    a2.x += w2 * v2.x; a2.y += w2 * v2.y; a2.z += w2 * v2.z; a2.w += w2 * v2.w;
    a3.x += w3 * v3.x; a3.y += w3 * v3.y; a3.z += w3 * v3.z; a3.w += w3 * v3.w;
  }
  for (; k < n1; k++) {
    int s = adj_in[p + k].x;
    float w = wi * dinv_in[s];
    float4 v = tin[(size_t)s * 32 + lane];
    a0.x += w * v.x; a0.y += w * v.y; a0.z += w * v.z; a0.w += w * v.w;
  }

  int q = rp_out[d], n2 = deg_out[d];
  k = 0;
  for (; k + 4 <= n2; k += 4) {
    int s0 = adj_out[q + k], s1 = adj_out[q + k + 1], s2 = adj_out[q + k + 2], s3 = adj_out[q + k + 3];
    float w0 = wo * dinv_out[s0], w1 = wo * dinv_out[s1], w2 = wo * dinv_out[s2], w3 = wo * dinv_out[s3];
    float4 v0 = tout[(size_t)s0 * 32 + lane];
    float4 v1 = tout[(size_t)s1 * 32 + lane];
    float4 v2 = tout[(size_t)s2 * 32 + lane];
    float4 v3 = tout[(size_t)s3 * 32 + lane];
    a0.x += w0 * v0.x; a0.y += w0 * v0.y; a0.z += w0 * v0.z; a0.w += w0 * v0.w;
    a1.x += w1 * v1.x; a1.y += w1 * v1.y; a1.z += w1 * v1.z; a1.w += w1 * v1.w;
    a2.x += w2 * v2.x; a2.y += w2 * v2.y; a2.z += w2 * v2.z; a2.w += w2 * v2.w;
    a3.x += w3 * v3.x; a3.y += w3 * v3.y; a3.z += w3 * v3.z; a3.w += w3 * v3.w;
  }
  for (; k < n2; k++) {
    int s = adj_out[q + k];
    float w = wo * dinv_out[s];
    float4 v = tout[(size_t)s * 32 + lane];
    a0.x += w * v.x; a0.y += w * v.y; a0.z += w * v.z; a0.w += w * v.w;
  }

  float4 acc;
  acc.x = (a0.x + a1.x) + (a2.x + a3.x);
  acc.y = (a0.y + a1.y) + (a2.y + a3.y);
  acc.z = (a0.z + a1.z) + (a2.z + a3.z);
  acc.w = (a0.w + a1.w) + (a2.w + a3.w);

  float4 ba = ((const float4*)bin)[lane], bb = ((const float4*)bout)[lane];
  float4 o;
  o.x = acc.x + 0.5f * (ba.x + bb.x);
  o.y = acc.y + 0.5f * (ba.y + bb.y);
  o.z = acc.z + 0.5f * (ba.z + bb.z);
  o.w = acc.w + 0.5f * (ba.w + bb.w);
  o.x = o.x > 0.f ? o.x : 0.f;
  o.y = o.y > 0.f ? o.y : 0.f;
  o.z = o.z > 0.f ? o.z : 0.f;
  o.w = o.w > 0.f ? o.w : 0.f;
  return o;
}

__device__ __forceinline__ float4 gat_node_val(int d, int lane,
    const float4* __restrict__ gl, const float4* __restrict__ gr,
    const int* __restrict__ rp, const int* __restrict__ deg, const int2* __restrict__ adj,
    const float* __restrict__ we, const float* __restrict__ att,
    const float* __restrict__ gatb) {
  float4 grv = gr[(size_t)d * 32 + lane];
  float4 wev = ((const float4*)we)[lane];
  float4 atv = ((const float4*)att)[lane];

  int p = rp[d], n1 = deg[d];
  float m = -1e30f, den = 0.f;
  float4 o = make_float4(0.f, 0.f, 0.f, 0.f);

#define GAT_LOGIT(g4, ea, pv)                                                     \
  {                                                                               \
    float vx = g4.x + grv.x + (ea) * wev.x; vx = vx > 0.f ? vx : 0.2f * vx;       \
    float vy = g4.y + grv.y + (ea) * wev.y; vy = vy > 0.f ? vy : 0.2f * vy;       \
    float vz = g4.z + grv.z + (ea) * wev.z; vz = vz > 0.f ? vz : 0.2f * vz;       \
    float vw = g4.w + grv.w + (ea) * wev.w; vw = vw > 0.f ? vw : 0.2f * vw;       \
    pv = vx * atv.x + vy * atv.y + vz * atv.z + vw * atv.w;                       \
    pv += __shfl_xor(pv, 1);                                                      \
    pv += __shfl_xor(pv, 2);                                                      \
    pv += __shfl_xor(pv, 4);                                                      \
  }

#define GAT_UPDATE(g4, pv)                                                        \
  {                                                                               \
    float mn = fmaxf(m, pv);                                                      \
    float sc = expf(m - mn);                                                      \
    float w = expf(pv - mn);                                                      \
    den = den * sc + w;                                                           \
    o.x = o.x * sc + w * g4.x;                                                    \
    o.y = o.y * sc + w * g4.y;                                                    \
    o.z = o.z * sc + w * g4.z;                                                    \
    o.w = o.w * sc + w * g4.w;                                                    \
    m = mn;                                                                       \
  }

  int k = 0;
  for (; k + 2 <= n1; k += 2) {
    int2 e0 = adj[p + k], e1 = adj[p + k + 1];
    float ea0 = __int_as_float(e0.y), ea1 = __int_as_float(e1.y);
    float4 g0 = gl[(size_t)e0.x * 32 + lane];
    float4 g1 = gl[(size_t)e1.x * 32 + lane];
    float pv0, pv1;
    GAT_LOGIT(g0, ea0, pv0);
    GAT_LOGIT(g1, ea1, pv1);
    GAT_UPDATE(g0, pv0);
    GAT_UPDATE(g1, pv1);
  }
  if (k < n1) {
    int2 e = adj[p + k];
    float ea = __int_as_float(e.y);
    float4 g = gl[(size_t)e.x * 32 + lane];
    float pv;
    GAT_LOGIT(g, ea, pv);
    GAT_UPDATE(g, pv);
  }
  {  // self loop: s = d, ea = 1.0
    float4 g = gl[(size_t)d * 32 + lane];
    float pv;
    GAT_LOGIT(g, 1.0f, pv);
    GAT_UPDATE(g, pv);
  }
#undef GAT_LOGIT
#undef GAT_UPDATE

  float4 bb = ((const float4*)gatb)[lane];
  float4 r;
  r.x = o.x / den + bb.x;
  r.y = o.y / den + bb.y;
  r.z = o.z / den + bb.z;
  r.w = o.w / den + bb.w;
  return r;
}

// dual matmul role body: 64-row tile, out0=A@W0 out1=A@W1 (As 32K + Ws 16K LDS)
__device__ __forceinline__ void mm64_dual(const float* __restrict__ A,
                                          const float* __restrict__ W0,
                                          const float* __restrict__ W1,
                                          float* __restrict__ out0,
                                          float* __restrict__ out1,
                                          int nrows, int r0, int tid,
                                          float (*As)[128], float (*Ws)[64]) {
#pragma unroll
  for (int i = 0; i < 8; i++) {
    int v = tid + 256 * i;
    int r = v >> 5, k4 = (v & 31) << 2;
    int row = r0 + r;
    float4 a;
    if (row < nrows) a = *(const float4*)(A + (size_t)row * FDIM + k4);
    else a = make_float4(0.f, 0.f, 0.f, 0.f);
    int swz = ((r >> 2) & 7) << 2;
    *(float4*)(&As[r][k4 ^ swz]) = a;
  }

  int tx = tid & 15, ty = tid >> 4;
  int rbase = ty * 4;
  int swz = (ty & 7) << 2;

  for (int p = 0; p < 4; p++) {
    const float* W = (p < 2) ? W0 : W1;
    float* out = (p < 2) ? out0 : out1;
    int cb = (p & 1) * 64;
    float acc[4][4] = {};

    for (int kh = 0; kh < 2; kh++) {
      __syncthreads();
#pragma unroll
      for (int i = 0; i < 4; i++) {
        int v = tid + 256 * i;
        int k = v >> 4, c4 = (v & 15) << 2;
        *(float4*)(&Ws[k][c4]) = *(const float4*)(W + (kh * 64 + k) * FDIM + cb + c4);
      }
      __syncthreads();

#pragma unroll 8
      for (int k = 0; k < 64; k++) {
        int kx = (kh * 64 + k) ^ swz;
        float a0 = As[rbase + 0][kx];
        float a1 = As[rbase + 1][kx];
        float a2 = As[rbase + 2][kx];
        float a3 = As[rbase + 3][kx];
        float4 w = *(float4*)(&Ws[k][tx * 4]);
        acc[0][0] += a0 * w.x; acc[0][1] += a0 * w.y; acc[0][2] += a0 * w.z; acc[0][3] += a0 * w.w;
        acc[1][0] += a1 * w.x; acc[1][1] += a1 * w.y; acc[1][2] += a1 * w.z; acc[1][3] += a1 * w.w;
        acc[2][0] += a2 * w.x; acc[2][1] += a2 * w.y; acc[2][2] += a2 * w.z; acc[2][3] += a2 * w.w;
        acc[3][0] += a3 * w.x; acc[3][1] += a3 * w.y; acc[3][2] += a3 * w.z; acc[3][3] += a3 * w.w;
      }
    }

#pragma unroll
    for (int rr = 0; rr < 4; rr++) {
      int row = r0 + rbase + rr;
      if (row < nrows) {
        float4 o = make_float4(acc[rr][0], acc[rr][1], acc[rr][2], acc[rr][3]);
        *(float4*)(out + (size_t)row * FDIM + cb + tx * 4) = o;
      }
    }
  }
}

// ================= fused heterogeneous kernels =================

// mmgat_degi: dual mm (x@wl->A, x@wr->B) || degree histogram
__global__ __launch_bounds__(256) void mmgat_degi(const float* __restrict__ x,
                                                  const float* __restrict__ wl,
                                                  const float* __restrict__ wr,
                                                  float* __restrict__ A,
                                                  float* __restrict__ B, int N, int mmB,
                                                  const int* __restrict__ src,
                                                  const int* __restrict__ dst,
                                                  int* __restrict__ deg_in,
                                                  int* __restrict__ deg_out, int E, int degB) {
  __shared__ float As[64][128];
  __shared__ float Ws[64][64];
  int T = mmB + degB;
  int bid = blockIdx.x, tid = threadIdx.x;
  long long f0 = (long long)bid * degB / T;
  long long f1 = (long long)(bid + 1) * degB / T;
  if (f1 > f0) {
    int base = ((int)f0 * 256 + tid) * 2;
    if (base + 2 <= E) {
      int2 s2 = *(const int2*)(src + base);
      int2 d2 = *(const int2*)(dst + base);
      atomicAdd(&deg_in[d2.x], 1);
      atomicAdd(&deg_in[d2.y], 1);
      atomicAdd(&deg_out[s2.x], 1);
      atomicAdd(&deg_out[s2.y], 1);
    } else {
      for (int i = base; i < E; i++) {
        atomicAdd(&deg_in[dst[i]], 1);
        atomicAdd(&deg_out[src[i]], 1);
      }
    }
    return;
  }
  int mb = bid - (int)f0;
  mm64_dual(x, wl, wr, A, B, N, mb * 64, tid, As, Ws);
}

// mm0_fill: dual mm (x@dwi, x@dwo) || CSR fill
__global__ __launch_bounds__(256) void mm0_fill(const float* __restrict__ x,
                                                const float* __restrict__ W0,
                                                const float* __restrict__ W1,
                                                float* __restrict__ out0,
                                                float* __restrict__ out1, int nrows, int mmB,
                                                const int* __restrict__ src,
                                                const int* __restrict__ dst,
                                                const float* __restrict__ eattr,
                                                int* __restrict__ cur_in,
                                                int* __restrict__ cur_out,
                                                int2* __restrict__ csr_in,
                                                int* __restrict__ csr_out_dst, int E, int fillB) {
  __shared__ float As[64][128];
  __shared__ float Ws[64][64];
  int T = mmB + fillB;
  int bid = blockIdx.x;
  int tid = threadIdx.x;
  long long f0 = (long long)bid * fillB / T;
  long long f1 = (long long)(bid + 1) * fillB / T;

  if (f1 > f0) {
    int base = ((int)f0 * 256 + tid) * 4;
    if (base + 4 <= E) {
      int4 s4 = *(const int4*)(src + base);
      int4 d4 = *(const int4*)(dst + base);
      float4 e4 = *(const float4*)(eattr + base);
      int p0 = atomicAdd(&cur_in[d4.x], 1);
      int p1 = atomicAdd(&cur_in[d4.y], 1);
      int p2 = atomicAdd(&cur_in[d4.z], 1);
      int p3 = atomicAdd(&cur_in[d4.w], 1);
      int q0 = atomicAdd(&cur_out[s4.x], 1);
      int q1 = atomicAdd(&cur_out[s4.y], 1);
      int q2 = atomicAdd(&cur_out[s4.z], 1);
      int q3 = atomicAdd(&cur_out[s4.w], 1);
      csr_in[p0] = make_int2(s4.x, __float_as_int(e4.x));
      csr_in[p1] = make_int2(s4.y, __float_as_int(e4.y));
      csr_in[p2] = make_int2(s4.z, __float_as_int(e4.z));
      csr_in[p3] = make_int2(s4.w, __float_as_int(e4.w));
      csr_out_dst[q0] = d4.x;
      csr_out_dst[q1] = d4.y;
      csr_out_dst[q2] = d4.z;
      csr_out_dst[q3] = d4.w;
    } else {
      for (int i = base; i < E; i++) {
        int s = src[i], d = dst[i];
        int p = atomicAdd(&cur_in[d], 1);
        csr_in[p] = make_int2(s, __float_as_int(eattr[i]));
        int q = atomicAdd(&cur_out[s], 1);
        csr_out_dst[q] = d;
      }
    }
    return;
  }

  int mb = bid - (int)f0;
  mm64_dual(x, W0, W1, out0, out1, nrows, mb * 64, tid, As, Ws);
}

// GAT aggregation + chunked-serial mean-pool (8 consecutive nodes / 32-lane group)
__global__ __launch_bounds__(128) void gat_pool8(const float4* __restrict__ gl,
                                                 const float4* __restrict__ gr,
                                                 const int* __restrict__ rp,
                                                 const int* __restrict__ deg,
                                                 const int2* __restrict__ adj,
                                                 const float* __restrict__ we,
                                                 const float* __restrict__ att,
                                                 const float* __restrict__ gatb,
                                                 const int* __restrict__ batch,
                                                 float* __restrict__ zb, int N) {
  int grp = threadIdx.x >> 5, lane = threadIdx.x & 31;
  int d0 = blockIdx.x * 32 + grp * 8;
  float4 run = make_float4(0.f, 0.f, 0.f, 0.f);
  int gp = -1;
  for (int i = 0; i < 8; i++) {
    int d = d0 + i;
    if (d >= N) break;
    int g = batch[d];
    if (g != gp) {
      if (gp >= 0) {
        float* ptr = &zb[(size_t)gp * 256 + 128 + lane * 4];
        atomicAdd(ptr + 0, run.x);
        atomicAdd(ptr + 1, run.y);
        atomicAdd(ptr + 2, run.z);
        atomicAdd(ptr + 3, run.w);
      }
      run = make_float4(0.f, 0.f, 0.f, 0.f);
      gp = g;
    }
    float4 r = gat_node_val(d, lane, gl, gr, rp, deg, adj, we, att, gatb);
    run.x += r.x; run.y += r.y; run.z += r.z; run.w += r.w;
  }
  if (gp >= 0) {
    float* ptr = &zb[(size_t)gp * 256 + 128 + lane * 4];
    atomicAdd(ptr + 0, run.x);
    atomicAdd(ptr + 1, run.y);
    atomicAdd(ptr + 2, run.z);
    atomicAdd(ptr + 3, run.w);
  }
}

// GCN gather -> dense output (layer 0)
__global__ __launch_bounds__(128) void gcn_gather4(const float4* __restrict__ tin,
                                                   const float4* __restrict__ tout,
                                                   const int* __restrict__ rp_in,
                                                   const int* __restrict__ deg_in,
                                                   const int2* __restrict__ adj_in,
                                                   const int* __restrict__ rp_out,
                                                   const int* __restrict__ deg_out,
                                                   const int* __restrict__ adj_out,
                                                   const float* __restrict__ dinv_in,
                                                   const float* __restrict__ dinv_out,
                                                   const float* __restrict__ bin,
                                                   const float* __restrict__ bout,
                                                   float4* __restrict__ outp, int N) {
  int grp = threadIdx.x >> 5, lane = threadIdx.x & 31;
  int d = blockIdx.x * 4 + grp;
  if (d >= N) return;
  float4 o = gcn_node_val(d, lane, tin, tout, rp_in, deg_in, adj_in,
                          rp_out, deg_out, adj_out, dinv_in, dinv_out, bin, bout);
  outp[(size_t)d * 32 + lane] = o;
}

// GCN gather (layer 1) + chunked-serial mean-pool (8 consecutive nodes / group)
__global__ __launch_bounds__(128) void gcn_pool8(
    const float4* __restrict__ tin, const float4* __restrict__ tout,
    const int* __restrict__ rp_in, const int* __restrict__ deg_in, const int2* __restrict__ adj_in,
    const int* __restrict__ rp_out, const int* __restrict__ deg_out, const int* __restrict__ adj_out,
    const float* __restrict__ dinv_in, const float* __restrict__ dinv_out,
    const float* __restrict__ bin, const float* __restrict__ bout,
    const int* __restrict__ batch, float* __restrict__ zb, int N) {
  int grp = threadIdx.x >> 5, lane = threadIdx.x & 31;
  int d0 = blockIdx.x * 32 + grp * 8;
  float4 run = make_float4(0.f, 0.f, 0.f, 0.f);
  int gp = -1;
  for (int i = 0; i < 8; i++) {
    int d = d0 + i;
    if (d >= N) break;
    int g = batch[d];
    if (g != gp) {
      if (gp >= 0) {
        float* ptr = &zb[(size_t)gp * 256 + lane * 4];
        atomicAdd(ptr + 0, run.x);
        atomicAdd(ptr + 1, run.y);
        atomicAdd(ptr + 2, run.z);
        atomicAdd(ptr + 3, run.w);
      }
      run = make_float4(0.f, 0.f, 0.f, 0.f);
      gp = g;
    }
    float4 o = gcn_node_val(d, lane, tin, tout, rp_in, deg_in, adj_in,
                            rp_out, deg_out, adj_out, dinv_in, dinv_out, bin, bout);
    run.x += o.x; run.y += o.y; run.z += o.z; run.w += o.w;
  }
  if (gp >= 0) {
    float* ptr = &zb[(size_t)gp * 256 + lane * 4];
    atomicAdd(ptr + 0, run.x);
    atomicAdd(ptr + 1, run.y);
    atomicAdd(ptr + 2, run.z);
    atomicAdd(ptr + 3, run.w);
  }
}

// standalone dual matmul
__global__ __launch_bounds__(256) void mm128d(const float* __restrict__ A,
                                              const float* __restrict__ W0,
                                              const float* __restrict__ W1,
                                              float* __restrict__ out0,
                                              float* __restrict__ out1, int nrows) {
  __shared__ float As[64][128];
  __shared__ float Ws[64][64];
  mm64_dual(A, W0, W1, out0, out1, nrows, blockIdx.x * 64, threadIdx.x, As, Ws);
}

// GAT -> dense output (fallback)
__global__ __launch_bounds__(128) void gat_fused2(const float4* __restrict__ gl,
                                                  const float4* __restrict__ gr,
                                                  const int* __restrict__ rp,
                                                  const int* __restrict__ deg,
                                                  const int2* __restrict__ adj,
                                                  const float* __restrict__ we,
                                                  const float* __restrict__ att,
                                                  const float* __restrict__ gatb,
                                                  float4* __restrict__ outp, int N) {
  int grp = threadIdx.x >> 5, lane = threadIdx.x & 31;
  int d = blockIdx.x * 4 + grp;
  if (d >= N) return;
  float4 r = gat_node_val(d, lane, gl, gr, rp, deg, adj, we, att, gatb);
  outp[(size_t)d * 32 + lane] = r;
}

// mean pool over dense buffer (fallback)
__global__ __launch_bounds__(128) void pool_kernel(const float* __restrict__ srcf,
                                                   const int* __restrict__ batch,
                                                   float* __restrict__ zb,
                                                   int colOff, int N) {
  __shared__ int sb[PCH];
  int c0 = blockIdx.x * PCH;
  int t = threadIdx.x;
  int nmax = N - c0; if (nmax > PCH) nmax = PCH;
  if (t < nmax) sb[t] = batch[c0 + t];
  __syncthreads();
  float run = 0.f;
  int gp = sb[0];
  for (int i = 0; i < nmax; i++) {
    int g = sb[i];
    if (g != gp) {
      atomicAdd(&zb[(size_t)gp * 256 + colOff + t], run);
      run = 0.f; gp = g;
    }
    run += srcf[(size_t)(c0 + i) * FDIM + t];
  }
  atomicAdd(&zb[(size_t)gp * 256 + colOff + t], run);
}

// ---------------- head ----------------
__global__ __launch_bounds__(128) void head_kernel(const float* __restrict__ zb,
                                                   const float* __restrict__ cnt,
                                                   const float* __restrict__ w1,
                                                   const float* __restrict__ b1,
                                                   const float* __restrict__ w2,
                                                   const float* __restrict__ b2,
                                                   float* __restrict__ out, int G) {
  __shared__ float z[256];
  __shared__ float y[128];
  int g = blockIdx.x, t = threadIdx.x;
  float c = cnt[g];
  float cm = c > 1.f ? c : 1.f;
  z[t]       = zb[(size_t)g * 256 + t] / cm;
  z[t + 128] = zb[(size_t)g * 256 + 128 + t] / cm;
  __syncthreads();
  float acc = b1[t];
  for (int k = 0; k < 256; k++) acc += z[k] * w1[k * 128 + t];
  y[t] = acc > 0.f ? acc : 0.f;
  __syncthreads();
  if (t < 2) {
    float o = b2[t];
    for (int j = 0; j < 128; j++) o += y[j] * w2[j * 2 + t];
    out[(size_t)g * 2 + t] = o;
  }
}

extern "C" void kernel_launch(void* const* d_in, const int* in_sizes, int n_in,
                              void* d_out, int out_size, void* d_ws, size_t ws_size,
                              hipStream_t stream) {
  const float* x     = (const float*)d_in[0];
  const int*   ei    = (const int*)d_in[1];
  const float* eattr = (const float*)d_in[2];
  const int*   batch = (const int*)d_in[3];
  const float* dwi   = (const float*)d_in[4];
  const float* dbi   = (const float*)d_in[5];
  const float* dwo   = (const float*)d_in[6];
  const float* dbo   = (const float*)d_in[7];
  const float* wl    = (const float*)d_in[8];
  const float* wr    = (const float*)d_in[9];
  const float* we    = (const float*)d_in[10];
  const float* att   = (const float*)d_in[11];
  const float* gatb  = (const float*)d_in[12];
  const float* w1    = (const float*)d_in[13];
  const float* b1    = (const float*)d_in[14];
  const float* w2    = (const float*)d_in[15];
  const float* b2    = (const float*)d_in[16];

  int N = in_sizes[0] / FDIM;
  int E = in_sizes[1] / 2;
  int G = out_size / 2;
  const int* src = ei;
  const int* dst = ei + E;

  size_t nf = (size_t)N * FDIM;
  size_t fixed = 10 * (size_t)N + 3 * (size_t)E + 512 + (size_t)G * 257;
  bool main_path = ((4 * nf + fixed) * sizeof(float)) <= ws_size;
  int nbuf = main_path ? 4 : 3;

  float* ws = (float*)d_ws;
  size_t off = 0;
  float* A = ws + off; off += nf;
  float* B = ws + off; off += nf;
  float* C = ws + off; off += nf;
  float* D = nullptr;
  if (nbuf == 4) { D = ws + off; off += nf; }
  float* dinv2    = ws + off; off += 2 * (size_t)N;
  int* deg2       = (int*)(ws + off); off += 2 * (size_t)N;
  int* rpt        = (int*)(ws + off); off += 2 * (size_t)N;
  int* rp_in      = (int*)(ws + off); off += (size_t)N;
  int* rp_out     = (int*)(ws + off); off += (size_t)N;
  int* cur_in     = (int*)(ws + off); off += (size_t)N;
  int* cur_out    = (int*)(ws + off); off += (size_t)N;
  int2* csr_in    = (int2*)(ws + off); off += 2 * (size_t)E;
  int* csr_out_dst= (int*)(ws + off); off += (size_t)E;
  int* bsums      = (int*)(ws + off); off += 256;
  int* boff       = (int*)(ws + off); off += 256;
  float* zb       = ws + off; off += (size_t)G * 256;
  float* cnt      = ws + off; off += (size_t)G;

  int* deg_in = deg2, *deg_out = deg2 + N;
  float* dinv_in = dinv2, *dinv_out = dinv2 + N;

  int n2 = 2 * N;
  int nb1 = cdiv(n2, 1024);
  int mmB = cdiv(N, 64);
  int fillB = cdiv(E, 1024);
  int degB = cdiv(E, 512);

  hipMemsetAsync(deg2, 0, (size_t)n2 * sizeof(int), stream);
  hipMemsetAsync(zb, 0, (size_t)G * 256 * sizeof(float), stream);

  if (main_path) {
    // S1: GAT transforms (x@wl->A, x@wr->B) || degree histogram
    mmgat_degi<<<mmB + degB, 256, 0, stream>>>(x, wl, wr, A, B, N, mmB,
                                               src, dst, deg_in, deg_out, E, degB);
    // S2: scans + counts
    dinv2_kernel<<<cdiv((long long)n2, 256), 256, 0, stream>>>(deg2, dinv2, n2);
    scan1<<<nb1, 256, 0, stream>>>(deg2, rpt, bsums, n2);
    scan2<<<1, 256, 0, stream>>>(bsums, boff, nb1);
    scan3<<<cdiv(n2, 256), 256, 0, stream>>>(rpt, boff, rp_in, cur_in, rp_out, cur_out, N, E, n2);
    cnt_sorted<<<cdiv(G, 256), 256, 0, stream>>>(batch, cnt, N, G);
    // S3: layer-0 transforms (x@dwi->C, x@dwo->D) || CSR fill
    mm0_fill<<<mmB + fillB, 256, 0, stream>>>(x, dwi, dwo, C, D, N, mmB,
                                              src, dst, eattr, cur_in, cur_out,
                                              csr_in, csr_out_dst, E, fillB);
    // S4: GAT aggregation + chunked pool (A,B -> zb[:,128:])
    gat_pool8<<<cdiv(N, 32), 128, 0, stream>>>((const float4*)A, (const float4*)B,
                                               rp_in, deg_in, csr_in,
                                               we, att, gatb, batch, zb, N);
    // S5: gather0 (C,D -> A)
    gcn_gather4<<<cdiv(N, 4), 128, 0, stream>>>((const float4*)C, (const float4*)D,
                                                rp_in, deg_in, csr_in,
                                                rp_out, deg_out, csr_out_dst,
                                                dinv_in, dinv_out, dbi, dbo, (float4*)A, N);
    // S6: layer-1 transforms (A@dwi1->C, A@dwo1->D)
    mm128d<<<mmB, 256, 0, stream>>>(A, dwi + 16384, dwo + 16384, C, D, N);
    // S7: gather1 + chunked pool (C,D -> zb[:,0:128])
    gcn_pool8<<<cdiv(N, 32), 128, 0, stream>>>((const float4*)C, (const float4*)D,
                                               rp_in, deg_in, csr_in,
                                               rp_out, deg_out, csr_out_dst,
                                               dinv_in, dinv_out, dbi + 128, dbo + 128,
                                               batch, zb, N);
  } else {
    // fallback: R9/R10-proven schedule (3 buffers, dense pools)
    degi_kernel<<<degB, 256, 0, stream>>>(src, dst, deg_in, deg_out, E);
    dinv2_kernel<<<cdiv((long long)n2, 256), 256, 0, stream>>>(deg2, dinv2, n2);
    scan1<<<nb1, 256, 0, stream>>>(deg2, rpt, bsums, n2);
    scan2<<<1, 256, 0, stream>>>(bsums, boff, nb1);
    scan3<<<cdiv(n2, 256), 256, 0, stream>>>(rpt, boff, rp_in, cur_in, rp_out, cur_out, N, E, n2);
    cnt_sorted<<<cdiv(G, 256), 256, 0, stream>>>(batch, cnt, N, G);
    mm0_fill<<<mmB + fillB, 256, 0, stream>>>(x, dwi, dwo, B, C, N, mmB,
                                              src, dst, eattr, cur_in, cur_out,
                                              csr_in, csr_out_dst, E, fillB);
    gcn_gather4<<<cdiv(N, 4), 128, 0, stream>>>((const float4*)B, (const float4*)C,
                                                rp_in, deg_in, csr_in,
                                                rp_out, deg_out, csr_out_dst,
                                                dinv_in, dinv_out, dbi, dbo, (float4*)A, N);
    mm128d<<<mmB, 256, 0, stream>>>(A, dwi + 16384, dwo + 16384, B, C, N);
    gcn_gather4<<<cdiv(N, 4), 128, 0, stream>>>((const float4*)B, (const float4*)C,
                                                rp_in, deg_in, csr_in,
                                                rp_out, deg_out, csr_out_dst,
                                                dinv_in, dinv_out, dbi + 128, dbo + 128, (float4*)A, N);
    pool_kernel<<<cdiv(N, PCH), 128, 0, stream>>>(A, batch, zb, 0, N);
    mm128d<<<mmB, 256, 0, stream>>>(x, wl, wr, B, C, N);
    gat_fused2<<<cdiv(N, 4), 128, 0, stream>>>((const float4*)B, (const float4*)C,
                                               rp_in, deg_in, csr_in,
                                               we, att, gatb, (float4*)A, N);
    pool_kernel<<<cdiv(N, PCH), 128, 0, stream>>>(A, batch, zb, 128, N);
  }

  // head
  head_kernel<<<G, 128, 0, stream>>>(zb, cnt, w1, b1, w2, b2, (float*)d_out, G);
}

// Round 14
// 1015.747 us; speedup vs baseline: 1.4537x; 1.0178x over previous
//
#include <hip/hip_runtime.h>
#include <cstdint>

#define FDIM 128
#define PCH 64

static inline int cdiv(long long a, long long b) { return (int)((a + b - 1) / b); }

// ---------------- degree histograms (standalone fallback) ----------------
__global__ __launch_bounds__(256) void degi_kernel(const int* __restrict__ src,
                                                   const int* __restrict__ dst,
                                                   int* __restrict__ deg_in,
                                                   int* __restrict__ deg_out, int E) {
  int base = (blockIdx.x * 256 + threadIdx.x) * 2;
  if (base + 2 <= E) {
    int2 s2 = *(const int2*)(src + base);
    int2 d2 = *(const int2*)(dst + base);
    atomicAdd(&deg_in[d2.x], 1);
    atomicAdd(&deg_in[d2.y], 1);
    atomicAdd(&deg_out[s2.x], 1);
    atomicAdd(&deg_out[s2.y], 1);
  } else {
    for (int i = base; i < E; i++) {
      atomicAdd(&deg_in[dst[i]], 1);
      atomicAdd(&deg_out[src[i]], 1);
    }
  }
}

__global__ __launch_bounds__(256) void dinv2_kernel(const int* __restrict__ degs,
                                                    float* __restrict__ dinv, int n2) {
  int i = blockIdx.x * 256 + threadIdx.x;
  if (i < n2) {
    int v = degs[i];
    dinv[i] = v > 0 ? 1.0f / sqrtf((float)v) : 0.f;
  }
}

// batch is sorted: cnt[g] = upper_bound(g) - lower_bound(g). No atomics.
__global__ __launch_bounds__(256) void cnt_sorted(const int* __restrict__ batch,
                                                  float* __restrict__ cnt, int N, int G) {
  int g = blockIdx.x * 256 + threadIdx.x;
  if (g >= G) return;
  int lo = 0, hi = N;
  while (lo < hi) { int mid = (lo + hi) >> 1; if (batch[mid] < g) lo = mid + 1; else hi = mid; }
  int lo2 = lo, hi2 = N;
  while (lo2 < hi2) { int mid = (lo2 + hi2) >> 1; if (batch[mid] <= g) lo2 = mid + 1; else hi2 = mid; }
  cnt[g] = (float)(lo2 - lo);
}

// ---------------- hierarchical exclusive scan over concatenated [deg_in|deg_out] ----------------
__global__ __launch_bounds__(256) void scan1(const int* __restrict__ in, int* __restrict__ out,
                                             int* __restrict__ bsums, int n) {
  __shared__ int tmp[256];
  int t = threadIdx.x;
  int base = blockIdx.x * 1024 + t * 4;
  int a[4];
#pragma unroll
  for (int j = 0; j < 4; j++) a[j] = (base + j < n) ? in[base + j] : 0;
  int s = a[0] + a[1] + a[2] + a[3];
  tmp[t] = s;
  __syncthreads();
  for (int off = 1; off < 256; off <<= 1) {
    int v = (t >= off) ? tmp[t - off] : 0;
    __syncthreads();
    tmp[t] += v;
    __syncthreads();
  }
  int excl = tmp[t] - s;
  int run = excl;
#pragma unroll
  for (int j = 0; j < 4; j++) {
    if (base + j < n) out[base + j] = run;
    run += a[j];
  }
  if (t == 255) bsums[blockIdx.x] = tmp[255];
}

__global__ __launch_bounds__(256) void scan2(const int* __restrict__ bsums,
                                             int* __restrict__ boff, int nb) {
  __shared__ int tmp[256];
  int t = threadIdx.x;
  int s = (t < nb) ? bsums[t] : 0;
  tmp[t] = s;
  __syncthreads();
  for (int off = 1; off < 256; off <<= 1) {
    int v = (t >= off) ? tmp[t - off] : 0;
    __syncthreads();
    tmp[t] += v;
    __syncthreads();
  }
  if (t < nb) boff[t] = tmp[t] - s;
}

__global__ __launch_bounds__(256) void scan3(const int* __restrict__ scanned,
                                             const int* __restrict__ boff,
                                             int* __restrict__ rp_in, int* __restrict__ cur_in,
                                             int* __restrict__ rp_out, int* __restrict__ cur_out,
                                             int N, int E, int n2) {
  int i = blockIdx.x * 256 + threadIdx.x;
  if (i < n2) {
    int v = scanned[i] + boff[i >> 10];
    if (i < N) { rp_in[i] = v; cur_in[i] = v; }
    else { v -= E; rp_out[i - N] = v; cur_out[i - N] = v; }
  }
}

// ================= shared device helpers =================

__device__ __forceinline__ float4 gcn_node_val(int d, int lane,
    const float4* __restrict__ tin, const float4* __restrict__ tout,
    const int* __restrict__ rp_in, const int* __restrict__ deg_in, const int2* __restrict__ adj_in,
    const int* __restrict__ rp_out, const int* __restrict__ deg_out, const int* __restrict__ adj_out,
    const float* __restrict__ dinv_in, const float* __restrict__ dinv_out,
    const float* __restrict__ bin, const float* __restrict__ bout) {
  float wi = 0.5f * dinv_in[d], wo = 0.5f * dinv_out[d];
  float4 a0 = make_float4(0.f, 0.f, 0.f, 0.f);
  float4 a1 = a0, a2 = a0, a3 = a0;

  int p = rp_in[d], n1 = deg_in[d];
  int k = 0;
  for (; k + 4 <= n1; k += 4) {
    int s0 = adj_in[p + k].x, s1 = adj_in[p + k + 1].x, s2 = adj_in[p + k + 2].x, s3 = adj_in[p + k + 3].x;
    float w0 = wi * dinv_in[s0], w1 = wi * dinv_in[s1], w2 = wi * dinv_in[s2], w3 = wi * dinv_in[s3];
    float4 v0 = tin[(size_t)s0 * 32 + lane];
    float4 v1 = tin[(size_t)s1 * 32 + lane];
    float4 v2 = tin[(size_t)s2 * 32 + lane];
    float4 v3 = tin[(size_t)s3 * 32 + lane];
    a0.x += w0 * v0.x; a0.y += w0 * v0.y; a0.z += w0 * v0.z; a0.w += w0 * v0.w;
    a1.x += w1 * v1.x; a1.y += w1 * v1.y; a1.z += w1 * v1.z; a1.w += w1 * v1.w;
    a2.x += w2 * v2.x; a2.y += w2 * v2.y; a2.z += w2 * v2.z; a2.w += w2 * v2.w;
    a3.x += w3 * v3.x; a3.y += w3 * v3.y; a3.z += w3 * v3.z; a3.w += w3 * v3.w;
  }
  for (; k < n1; k++) {
    int s = adj_in[p + k].x;
    float w = wi * dinv_in[s];
    float4 v = tin[(size_t)s * 32 + lane];
    a0.x += w * v.x; a0.y += w * v.y; a0.z += w * v.z; a0.w += w * v.w;
  }

  int q = rp_out[d], n2 = deg_out[d];
  k = 0;
  for (; k + 4 <= n2; k += 4) {
    int s0 = adj_out[q + k], s1 = adj_out[q + k + 1], s2 = adj_out[q + k + 2], s3 = adj_out[q + k + 3];
    float w0 = wo * dinv_out[s0], w1 = wo * dinv_out[s1], w2 = wo * dinv_out[s2], w3 = wo * dinv_out[s3];
    float4 v0 = tout[(size_t)s0 * 32 + lane];
    float4 v1 = tout[(size_t)s1 * 32 + lane];
    float4 v2 = tout[(size_t)s2 * 32 + lane];
    float4 v3 = tout[(size_t)s3 * 32 + lane];
    a0.x += w0 * v0.x; a0.y += w0 * v0.y; a0.z += w0 * v0.z; a0.w += w0 * v0.w;
    a1.x += w1 * v1.x; a1.y += w1 * v1.y; a1.z += w1 * v1.z; a1.w += w1 * v1.w;
    a2.x += w2 * v2.x; a2.y += w2 * v2.y; a2.z += w2 * v2.z; a2.w += w2 * v2.w;
    a3.x += w3 * v3.x; a3.y += w3 * v3.y; a3.z += w3 * v3.z; a3.w += w3 * v3.w;
  }
  for (; k < n2; k++) {
    int s = adj_out[q + k];
    float w = wo * dinv_out[s];
    float4 v = tout[(size_t)s * 32 + lane];
    a0.x += w * v.x; a0.y += w * v.y; a0.z += w * v.z; a0.w += w * v.w;
  }

  float4 acc;
  acc.x = (a0.x + a1.x) + (a2.x + a3.x);
  acc.y = (a0.y + a1.y) + (a2.y + a3.y);
  acc.z = (a0.z + a1.z) + (a2.z + a3.z);
  acc.w = (a0.w + a1.w) + (a2.w + a3.w);

  float4 ba = ((const float4*)bin)[lane], bb = ((const float4*)bout)[lane];
  float4 o;
  o.x = acc.x + 0.5f * (ba.x + bb.x);
  o.y = acc.y + 0.5f * (ba.y + bb.y);
  o.z = acc.z + 0.5f * (ba.z + bb.z);
  o.w = acc.w + 0.5f * (ba.w + bb.w);
  o.x = o.x > 0.f ? o.x : 0.f;
  o.y = o.y > 0.f ? o.y : 0.f;
  o.z = o.z > 0.f ? o.z : 0.f;
  o.w = o.w > 0.f ? o.w : 0.f;
  return o;
}

__device__ __forceinline__ float4 gat_node_val(int d, int lane,
    const float4* __restrict__ gl, const float4* __restrict__ gr,
    const int* __restrict__ rp, const int* __restrict__ deg, const int2* __restrict__ adj,
    const float* __restrict__ we, const float* __restrict__ att,
    const float* __restrict__ gatb) {
  float4 grv = gr[(size_t)d * 32 + lane];
  float4 wev = ((const float4*)we)[lane];
  float4 atv = ((const float4*)att)[lane];

  int p = rp[d], n1 = deg[d];
  float m = -1e30f, den = 0.f;
  float4 o = make_float4(0.f, 0.f, 0.f, 0.f);

#define GAT_LOGIT(g4, ea, pv)                                                     \
  {                                                                               \
    float vx = g4.x + grv.x + (ea) * wev.x; vx = vx > 0.f ? vx : 0.2f * vx;       \
    float vy = g4.y + grv.y + (ea) * wev.y; vy = vy > 0.f ? vy : 0.2f * vy;       \
    float vz = g4.z + grv.z + (ea) * wev.z; vz = vz > 0.f ? vz : 0.2f * vz;       \
    float vw = g4.w + grv.w + (ea) * wev.w; vw = vw > 0.f ? vw : 0.2f * vw;       \
    pv = vx * atv.x + vy * atv.y + vz * atv.z + vw * atv.w;                       \
    pv += __shfl_xor(pv, 1);                                                      \
    pv += __shfl_xor(pv, 2);                                                      \
    pv += __shfl_xor(pv, 4);                                                      \
  }

#define GAT_UPDATE(g4, pv)                                                        \
  {                                                                               \
    float mn = fmaxf(m, pv);                                                      \
    float sc = expf(m - mn);                                                      \
    float w = expf(pv - mn);                                                      \
    den = den * sc + w;                                                           \
    o.x = o.x * sc + w * g4.x;                                                    \
    o.y = o.y * sc + w * g4.y;                                                    \
    o.z = o.z * sc + w * g4.z;                                                    \
    o.w = o.w * sc + w * g4.w;                                                    \
    m = mn;                                                                       \
  }

  int k = 0;
  for (; k + 2 <= n1; k += 2) {
    int2 e0 = adj[p + k], e1 = adj[p + k + 1];
    float ea0 = __int_as_float(e0.y), ea1 = __int_as_float(e1.y);
    float4 g0 = gl[(size_t)e0.x * 32 + lane];
    float4 g1 = gl[(size_t)e1.x * 32 + lane];
    float pv0, pv1;
    GAT_LOGIT(g0, ea0, pv0);
    GAT_LOGIT(g1, ea1, pv1);
    GAT_UPDATE(g0, pv0);
    GAT_UPDATE(g1, pv1);
  }
  if (k < n1) {
    int2 e = adj[p + k];
    float ea = __int_as_float(e.y);
    float4 g = gl[(size_t)e.x * 32 + lane];
    float pv;
    GAT_LOGIT(g, ea, pv);
    GAT_UPDATE(g, pv);
  }
  {  // self loop: s = d, ea = 1.0
    float4 g = gl[(size_t)d * 32 + lane];
    float pv;
    GAT_LOGIT(g, 1.0f, pv);
    GAT_UPDATE(g, pv);
  }
#undef GAT_LOGIT
#undef GAT_UPDATE

  float4 bb = ((const float4*)gatb)[lane];
  float4 r;
  r.x = o.x / den + bb.x;
  r.y = o.y / den + bb.y;
  r.z = o.z / den + bb.z;
  r.w = o.w / den + bb.w;
  return r;
}

// dual matmul role body: 64-row tile, out0=A@W0 out1=A@W1 (As 32K + Ws 16K LDS)
__device__ __forceinline__ void mm64_dual(const float* __restrict__ A,
                                          const float* __restrict__ W0,
                                          const float* __restrict__ W1,
                                          float* __restrict__ out0,
                                          float* __restrict__ out1,
                                          int nrows, int r0, int tid,
                                          float (*As)[128], float (*Ws)[64]) {
#pragma unroll
  for (int i = 0; i < 8; i++) {
    int v = tid + 256 * i;
    int r = v >> 5, k4 = (v & 31) << 2;
    int row = r0 + r;
    float4 a;
    if (row < nrows) a = *(const float4*)(A + (size_t)row * FDIM + k4);
    else a = make_float4(0.f, 0.f, 0.f, 0.f);
    int swz = ((r >> 2) & 7) << 2;
    *(float4*)(&As[r][k4 ^ swz]) = a;
  }

  int tx = tid & 15, ty = tid >> 4;
  int rbase = ty * 4;
  int swz = (ty & 7) << 2;

  for (int p = 0; p < 4; p++) {
    const float* W = (p < 2) ? W0 : W1;
    float* out = (p < 2) ? out0 : out1;
    int cb = (p & 1) * 64;
    float acc[4][4] = {};

    for (int kh = 0; kh < 2; kh++) {
      __syncthreads();
#pragma unroll
      for (int i = 0; i < 4; i++) {
        int v = tid + 256 * i;
        int k = v >> 4, c4 = (v & 15) << 2;
        *(float4*)(&Ws[k][c4]) = *(const float4*)(W + (kh * 64 + k) * FDIM + cb + c4);
      }
      __syncthreads();

#pragma unroll 8
      for (int k = 0; k < 64; k++) {
        int kx = (kh * 64 + k) ^ swz;
        float a0 = As[rbase + 0][kx];
        float a1 = As[rbase + 1][kx];
        float a2 = As[rbase + 2][kx];
        float a3 = As[rbase + 3][kx];
        float4 w = *(float4*)(&Ws[k][tx * 4]);
        acc[0][0] += a0 * w.x; acc[0][1] += a0 * w.y; acc[0][2] += a0 * w.z; acc[0][3] += a0 * w.w;
        acc[1][0] += a1 * w.x; acc[1][1] += a1 * w.y; acc[1][2] += a1 * w.z; acc[1][3] += a1 * w.w;
        acc[2][0] += a2 * w.x; acc[2][1] += a2 * w.y; acc[2][2] += a2 * w.z; acc[2][3] += a2 * w.w;
        acc[3][0] += a3 * w.x; acc[3][1] += a3 * w.y; acc[3][2] += a3 * w.z; acc[3][3] += a3 * w.w;
      }
    }

#pragma unroll
    for (int rr = 0; rr < 4; rr++) {
      int row = r0 + rbase + rr;
      if (row < nrows) {
        float4 o = make_float4(acc[rr][0], acc[rr][1], acc[rr][2], acc[rr][3]);
        *(float4*)(out + (size_t)row * FDIM + cb + tx * 4) = o;
      }
    }
  }
}

// ================= fused heterogeneous kernels =================

// mmgat_degi: dual mm (x@wl->A, x@wr->B) || degree histogram
__global__ __launch_bounds__(256) void mmgat_degi(const float* __restrict__ x,
                                                  const float* __restrict__ wl,
                                                  const float* __restrict__ wr,
                                                  float* __restrict__ A,
                                                  float* __restrict__ B, int N, int mmB,
                                                  const int* __restrict__ src,
                                                  const int* __restrict__ dst,
                                                  int* __restrict__ deg_in,
                                                  int* __restrict__ deg_out, int E, int degB) {
  __shared__ float As[64][128];
  __shared__ float Ws[64][64];
  int T = mmB + degB;
  int bid = blockIdx.x, tid = threadIdx.x;
  long long f0 = (long long)bid * degB / T;
  long long f1 = (long long)(bid + 1) * degB / T;
  if (f1 > f0) {
    int base = ((int)f0 * 256 + tid) * 2;
    if (base + 2 <= E) {
      int2 s2 = *(const int2*)(src + base);
      int2 d2 = *(const int2*)(dst + base);
      atomicAdd(&deg_in[d2.x], 1);
      atomicAdd(&deg_in[d2.y], 1);
      atomicAdd(&deg_out[s2.x], 1);
      atomicAdd(&deg_out[s2.y], 1);
    } else {
      for (int i = base; i < E; i++) {
        atomicAdd(&deg_in[dst[i]], 1);
        atomicAdd(&deg_out[src[i]], 1);
      }
    }
    return;
  }
  int mb = bid - (int)f0;
  mm64_dual(x, wl, wr, A, B, N, mb * 64, tid, As, Ws);
}

// mm0_fill: dual mm (x@dwi, x@dwo) || CSR fill
__global__ __launch_bounds__(256) void mm0_fill(const float* __restrict__ x,
                                                const float* __restrict__ W0,
                                                const float* __restrict__ W1,
                                                float* __restrict__ out0,
                                                float* __restrict__ out1, int nrows, int mmB,
                                                const int* __restrict__ src,
                                                const int* __restrict__ dst,
                                                const float* __restrict__ eattr,
                                                int* __restrict__ cur_in,
                                                int* __restrict__ cur_out,
                                                int2* __restrict__ csr_in,
                                                int* __restrict__ csr_out_dst, int E, int fillB) {
  __shared__ float As[64][128];
  __shared__ float Ws[64][64];
  int T = mmB + fillB;
  int bid = blockIdx.x;
  int tid = threadIdx.x;
  long long f0 = (long long)bid * fillB / T;
  long long f1 = (long long)(bid + 1) * fillB / T;

  if (f1 > f0) {
    int base = ((int)f0 * 256 + tid) * 4;
    if (base + 4 <= E) {
      int4 s4 = *(const int4*)(src + base);
      int4 d4 = *(const int4*)(dst + base);
      float4 e4 = *(const float4*)(eattr + base);
      int p0 = atomicAdd(&cur_in[d4.x], 1);
      int p1 = atomicAdd(&cur_in[d4.y], 1);
      int p2 = atomicAdd(&cur_in[d4.z], 1);
      int p3 = atomicAdd(&cur_in[d4.w], 1);
      int q0 = atomicAdd(&cur_out[s4.x], 1);
      int q1 = atomicAdd(&cur_out[s4.y], 1);
      int q2 = atomicAdd(&cur_out[s4.z], 1);
      int q3 = atomicAdd(&cur_out[s4.w], 1);
      csr_in[p0] = make_int2(s4.x, __float_as_int(e4.x));
      csr_in[p1] = make_int2(s4.y, __float_as_int(e4.y));
      csr_in[p2] = make_int2(s4.z, __float_as_int(e4.z));
      csr_in[p3] = make_int2(s4.w, __float_as_int(e4.w));
      csr_out_dst[q0] = d4.x;
      csr_out_dst[q1] = d4.y;
      csr_out_dst[q2] = d4.z;
      csr_out_dst[q3] = d4.w;
    } else {
      for (int i = base; i < E; i++) {
        int s = src[i], d = dst[i];
        int p = atomicAdd(&cur_in[d], 1);
        csr_in[p] = make_int2(s, __float_as_int(eattr[i]));
        int q = atomicAdd(&cur_out[s], 1);
        csr_out_dst[q] = d;
      }
    }
    return;
  }

  int mb = bid - (int)f0;
  mm64_dual(x, W0, W1, out0, out1, nrows, mb * 64, tid, As, Ws);
}

// gath0_mm1: gather0 tile directly into LDS, then dual mm1 from LDS.
// 32-row tile: 8 groups x 4 nodes gather phase; mm32-style compute (2 rows/thread).
__global__ __launch_bounds__(256) void gath0_mm1(
    const float4* __restrict__ tin, const float4* __restrict__ tout,
    const int* __restrict__ rp_in, const int* __restrict__ deg_in, const int2* __restrict__ adj_in,
    const int* __restrict__ rp_out, const int* __restrict__ deg_out, const int* __restrict__ adj_out,
    const float* __restrict__ dinv_in, const float* __restrict__ dinv_out,
    const float* __restrict__ bin, const float* __restrict__ bout,
    const float* __restrict__ W0, const float* __restrict__ W1,
    float* __restrict__ out0, float* __restrict__ out1, int N) {
  __shared__ float As[32][128];
  __shared__ float Ws[64][64];
  int r0 = blockIdx.x * 32;
  int tid = threadIdx.x;
  int grp = tid >> 5, lane = tid & 31;

  // gather phase: each 32-lane group produces 4 consecutive rows into As (swizzled)
  for (int i = 0; i < 4; i++) {
    int r = grp * 4 + i;
    int d = r0 + r;
    int wsz = ((r >> 2) & 7) << 2;
    float4 o;
    if (d < N) {
      o = gcn_node_val(d, lane, tin, tout, rp_in, deg_in, adj_in,
                       rp_out, deg_out, adj_out, dinv_in, dinv_out, bin, bout);
    } else {
      o = make_float4(0.f, 0.f, 0.f, 0.f);
    }
    *(float4*)(&As[r][(lane * 4) ^ wsz]) = o;
  }

  // mm phase (mm32_dual compute; As already staged)
  int tx = tid & 15, ty = tid >> 4;
  int rbase = ty * 2;
  int swz = ((ty >> 1) & 7) << 2;

  for (int p = 0; p < 4; p++) {
    const float* W = (p < 2) ? W0 : W1;
    float* out = (p < 2) ? out0 : out1;
    int cb = (p & 1) * 64;
    float acc[2][4] = {};

    for (int kh = 0; kh < 2; kh++) {
      __syncthreads();  // As ready (p=0,kh=0) / previous compute done reading Ws
#pragma unroll
      for (int i = 0; i < 4; i++) {
        int v = tid + 256 * i;
        int k = v >> 4, c4 = (v & 15) << 2;
        *(float4*)(&Ws[k][c4]) = *(const float4*)(W + (kh * 64 + k) * FDIM + cb + c4);
      }
      __syncthreads();

#pragma unroll 8
      for (int k = 0; k < 64; k++) {
        int kx = (kh * 64 + k) ^ swz;
        float a0 = As[rbase + 0][kx];
        float a1 = As[rbase + 1][kx];
        float4 w = *(float4*)(&Ws[k][tx * 4]);
        acc[0][0] += a0 * w.x; acc[0][1] += a0 * w.y; acc[0][2] += a0 * w.z; acc[0][3] += a0 * w.w;
        acc[1][0] += a1 * w.x; acc[1][1] += a1 * w.y; acc[1][2] += a1 * w.z; acc[1][3] += a1 * w.w;
      }
    }

#pragma unroll
    for (int rr = 0; rr < 2; rr++) {
      int row = r0 + rbase + rr;
      if (row < N) {
        float4 o = make_float4(acc[rr][0], acc[rr][1], acc[rr][2], acc[rr][3]);
        *(float4*)(out + (size_t)row * FDIM + cb + tx * 4) = o;
      }
    }
  }
}

// GAT aggregation + chunked-serial mean-pool (8 consecutive nodes / 32-lane group)
__global__ __launch_bounds__(128) void gat_pool8(const float4* __restrict__ gl,
                                                 const float4* __restrict__ gr,
                                                 const int* __restrict__ rp,
                                                 const int* __restrict__ deg,
                                                 const int2* __restrict__ adj,
                                                 const float* __restrict__ we,
                                                 const float* __restrict__ att,
                                                 const float* __restrict__ gatb,
                                                 const int* __restrict__ batch,
                                                 float* __restrict__ zb, int N) {
  int grp = threadIdx.x >> 5, lane = threadIdx.x & 31;
  int d0 = blockIdx.x * 32 + grp * 8;
  float4 run = make_float4(0.f, 0.f, 0.f, 0.f);
  int gp = -1;
  for (int i = 0; i < 8; i++) {
    int d = d0 + i;
    if (d >= N) break;
    int g = batch[d];
    if (g != gp) {
      if (gp >= 0) {
        float* ptr = &zb[(size_t)gp * 256 + 128 + lane * 4];
        atomicAdd(ptr + 0, run.x);
        atomicAdd(ptr + 1, run.y);
        atomicAdd(ptr + 2, run.z);
        atomicAdd(ptr + 3, run.w);
      }
      run = make_float4(0.f, 0.f, 0.f, 0.f);
      gp = g;
    }
    float4 r = gat_node_val(d, lane, gl, gr, rp, deg, adj, we, att, gatb);
    run.x += r.x; run.y += r.y; run.z += r.z; run.w += r.w;
  }
  if (gp >= 0) {
    float* ptr = &zb[(size_t)gp * 256 + 128 + lane * 4];
    atomicAdd(ptr + 0, run.x);
    atomicAdd(ptr + 1, run.y);
    atomicAdd(ptr + 2, run.z);
    atomicAdd(ptr + 3, run.w);
  }
}

// GCN gather -> dense output (fallback layer 0)
__global__ __launch_bounds__(128) void gcn_gather4(const float4* __restrict__ tin,
                                                   const float4* __restrict__ tout,
                                                   const int* __restrict__ rp_in,
                                                   const int* __restrict__ deg_in,
                                                   const int2* __restrict__ adj_in,
                                                   const int* __restrict__ rp_out,
                                                   const int* __restrict__ deg_out,
                                                   const int* __restrict__ adj_out,
                                                   const float* __restrict__ dinv_in,
                                                   const float* __restrict__ dinv_out,
                                                   const float* __restrict__ bin,
                                                   const float* __restrict__ bout,
                                                   float4* __restrict__ outp, int N) {
  int grp = threadIdx.x >> 5, lane = threadIdx.x & 31;
  int d = blockIdx.x * 4 + grp;
  if (d >= N) return;
  float4 o = gcn_node_val(d, lane, tin, tout, rp_in, deg_in, adj_in,
                          rp_out, deg_out, adj_out, dinv_in, dinv_out, bin, bout);
  outp[(size_t)d * 32 + lane] = o;
}

// GCN gather (layer 1) + chunked-serial mean-pool (8 consecutive nodes / group)
__global__ __launch_bounds__(128) void gcn_pool8(
    const float4* __restrict__ tin, const float4* __restrict__ tout,
    const int* __restrict__ rp_in, const int* __restrict__ deg_in, const int2* __restrict__ adj_in,
    const int* __restrict__ rp_out, const int* __restrict__ deg_out, const int* __restrict__ adj_out,
    const float* __restrict__ dinv_in, const float* __restrict__ dinv_out,
    const float* __restrict__ bin, const float* __restrict__ bout,
    const int* __restrict__ batch, float* __restrict__ zb, int N) {
  int grp = threadIdx.x >> 5, lane = threadIdx.x & 31;
  int d0 = blockIdx.x * 32 + grp * 8;
  float4 run = make_float4(0.f, 0.f, 0.f, 0.f);
  int gp = -1;
  for (int i = 0; i < 8; i++) {
    int d = d0 + i;
    if (d >= N) break;
    int g = batch[d];
    if (g != gp) {
      if (gp >= 0) {
        float* ptr = &zb[(size_t)gp * 256 + lane * 4];
        atomicAdd(ptr + 0, run.x);
        atomicAdd(ptr + 1, run.y);
        atomicAdd(ptr + 2, run.z);
        atomicAdd(ptr + 3, run.w);
      }
      run = make_float4(0.f, 0.f, 0.f, 0.f);
      gp = g;
    }
    float4 o = gcn_node_val(d, lane, tin, tout, rp_in, deg_in, adj_in,
                            rp_out, deg_out, adj_out, dinv_in, dinv_out, bin, bout);
    run.x += o.x; run.y += o.y; run.z += o.z; run.w += o.w;
  }
  if (gp >= 0) {
    float* ptr = &zb[(size_t)gp * 256 + lane * 4];
    atomicAdd(ptr + 0, run.x);
    atomicAdd(ptr + 1, run.y);
    atomicAdd(ptr + 2, run.z);
    atomicAdd(ptr + 3, run.w);
  }
}

// standalone dual matmul (fallback)
__global__ __launch_bounds__(256) void mm128d(const float* __restrict__ A,
                                              const float* __restrict__ W0,
                                              const float* __restrict__ W1,
                                              float* __restrict__ out0,
                                              float* __restrict__ out1, int nrows) {
  __shared__ float As[64][128];
  __shared__ float Ws[64][64];
  mm64_dual(A, W0, W1, out0, out1, nrows, blockIdx.x * 64, threadIdx.x, As, Ws);
}

// GAT -> dense output (fallback)
__global__ __launch_bounds__(128) void gat_fused2(const float4* __restrict__ gl,
                                                  const float4* __restrict__ gr,
                                                  const int* __restrict__ rp,
                                                  const int* __restrict__ deg,
                                                  const int2* __restrict__ adj,
                                                  const float* __restrict__ we,
                                                  const float* __restrict__ att,
                                                  const float* __restrict__ gatb,
                                                  float4* __restrict__ outp, int N) {
  int grp = threadIdx.x >> 5, lane = threadIdx.x & 31;
  int d = blockIdx.x * 4 + grp;
  if (d >= N) return;
  float4 r = gat_node_val(d, lane, gl, gr, rp, deg, adj, we, att, gatb);
  outp[(size_t)d * 32 + lane] = r;
}

// mean pool over dense buffer (fallback)
__global__ __launch_bounds__(128) void pool_kernel(const float* __restrict__ srcf,
                                                   const int* __restrict__ batch,
                                                   float* __restrict__ zb,
                                                   int colOff, int N) {
  __shared__ int sb[PCH];
  int c0 = blockIdx.x * PCH;
  int t = threadIdx.x;
  int nmax = N - c0; if (nmax > PCH) nmax = PCH;
  if (t < nmax) sb[t] = batch[c0 + t];
  __syncthreads();
  float run = 0.f;
  int gp = sb[0];
  for (int i = 0; i < nmax; i++) {
    int g = sb[i];
    if (g != gp) {
      atomicAdd(&zb[(size_t)gp * 256 + colOff + t], run);
      run = 0.f; gp = g;
    }
    run += srcf[(size_t)(c0 + i) * FDIM + t];
  }
  atomicAdd(&zb[(size_t)gp * 256 + colOff + t], run);
}

// ---------------- head ----------------
__global__ __launch_bounds__(128) void head_kernel(const float* __restrict__ zb,
                                                   const float* __restrict__ cnt,
                                                   const float* __restrict__ w1,
                                                   const float* __restrict__ b1,
                                                   const float* __restrict__ w2,
                                                   const float* __restrict__ b2,
                                                   float* __restrict__ out, int G) {
  __shared__ float z[256];
  __shared__ float y[128];
  int g = blockIdx.x, t = threadIdx.x;
  float c = cnt[g];
  float cm = c > 1.f ? c : 1.f;
  z[t]       = zb[(size_t)g * 256 + t] / cm;
  z[t + 128] = zb[(size_t)g * 256 + 128 + t] / cm;
  __syncthreads();
  float acc = b1[t];
  for (int k = 0; k < 256; k++) acc += z[k] * w1[k * 128 + t];
  y[t] = acc > 0.f ? acc : 0.f;
  __syncthreads();
  if (t < 2) {
    float o = b2[t];
    for (int j = 0; j < 128; j++) o += y[j] * w2[j * 2 + t];
    out[(size_t)g * 2 + t] = o;
  }
}

extern "C" void kernel_launch(void* const* d_in, const int* in_sizes, int n_in,
                              void* d_out, int out_size, void* d_ws, size_t ws_size,
                              hipStream_t stream) {
  const float* x     = (const float*)d_in[0];
  const int*   ei    = (const int*)d_in[1];
  const float* eattr = (const float*)d_in[2];
  const int*   batch = (const int*)d_in[3];
  const float* dwi   = (const float*)d_in[4];
  const float* dbi   = (const float*)d_in[5];
  const float* dwo   = (const float*)d_in[6];
  const float* dbo   = (const float*)d_in[7];
  const float* wl    = (const float*)d_in[8];
  const float* wr    = (const float*)d_in[9];
  const float* we    = (const float*)d_in[10];
  const float* att   = (const float*)d_in[11];
  const float* gatb  = (const float*)d_in[12];
  const float* w1    = (const float*)d_in[13];
  const float* b1    = (const float*)d_in[14];
  const float* w2    = (const float*)d_in[15];
  const float* b2    = (const float*)d_in[16];

  int N = in_sizes[0] / FDIM;
  int E = in_sizes[1] / 2;
  int G = out_size / 2;
  const int* src = ei;
  const int* dst = ei + E;

  size_t nf = (size_t)N * FDIM;
  size_t fixed = 10 * (size_t)N + 3 * (size_t)E + 512 + (size_t)G * 257;
  bool main_path = ((4 * nf + fixed) * sizeof(float)) <= ws_size;
  int nbuf = main_path ? 4 : 3;

  float* ws = (float*)d_ws;
  size_t off = 0;
  float* A = ws + off; off += nf;
  float* B = ws + off; off += nf;
  float* C = ws + off; off += nf;
  float* D = nullptr;
  if (nbuf == 4) { D = ws + off; off += nf; }
  float* dinv2    = ws + off; off += 2 * (size_t)N;
  int* deg2       = (int*)(ws + off); off += 2 * (size_t)N;
  int* rpt        = (int*)(ws + off); off += 2 * (size_t)N;
  int* rp_in      = (int*)(ws + off); off += (size_t)N;
  int* rp_out     = (int*)(ws + off); off += (size_t)N;
  int* cur_in     = (int*)(ws + off); off += (size_t)N;
  int* cur_out    = (int*)(ws + off); off += (size_t)N;
  int2* csr_in    = (int2*)(ws + off); off += 2 * (size_t)E;
  int* csr_out_dst= (int*)(ws + off); off += (size_t)E;
  int* bsums      = (int*)(ws + off); off += 256;
  int* boff       = (int*)(ws + off); off += 256;
  float* zb       = ws + off; off += (size_t)G * 256;
  float* cnt      = ws + off; off += (size_t)G;

  int* deg_in = deg2, *deg_out = deg2 + N;
  float* dinv_in = dinv2, *dinv_out = dinv2 + N;

  int n2 = 2 * N;
  int nb1 = cdiv(n2, 1024);
  int mmB = cdiv(N, 64);
  int fillB = cdiv(E, 1024);
  int degB = cdiv(E, 512);

  hipMemsetAsync(deg2, 0, (size_t)n2 * sizeof(int), stream);
  hipMemsetAsync(zb, 0, (size_t)G * 256 * sizeof(float), stream);

  if (main_path) {
    // S1: GAT transforms (x@wl->A, x@wr->B) || degree histogram
    mmgat_degi<<<mmB + degB, 256, 0, stream>>>(x, wl, wr, A, B, N, mmB,
                                               src, dst, deg_in, deg_out, E, degB);
    // S2: scans + counts
    dinv2_kernel<<<cdiv((long long)n2, 256), 256, 0, stream>>>(deg2, dinv2, n2);
    scan1<<<nb1, 256, 0, stream>>>(deg2, rpt, bsums, n2);
    scan2<<<1, 256, 0, stream>>>(bsums, boff, nb1);
    scan3<<<cdiv(n2, 256), 256, 0, stream>>>(rpt, boff, rp_in, cur_in, rp_out, cur_out, N, E, n2);
    cnt_sorted<<<cdiv(G, 256), 256, 0, stream>>>(batch, cnt, N, G);
    // S3: layer-0 transforms (x@dwi->C, x@dwo->D) || CSR fill
    mm0_fill<<<mmB + fillB, 256, 0, stream>>>(x, dwi, dwo, C, D, N, mmB,
                                              src, dst, eattr, cur_in, cur_out,
                                              csr_in, csr_out_dst, E, fillB);
    // S4: GAT aggregation + chunked pool (A,B -> zb[:,128:]) — frees A,B
    gat_pool8<<<cdiv(N, 32), 128, 0, stream>>>((const float4*)A, (const float4*)B,
                                               rp_in, deg_in, csr_in,
                                               we, att, gatb, batch, zb, N);
    // S5+S6 fused: gather0 (C,D) -> LDS tile -> mm1 -> A,B
    gath0_mm1<<<cdiv(N, 32), 256, 0, stream>>>((const float4*)C, (const float4*)D,
                                               rp_in, deg_in, csr_in,
                                               rp_out, deg_out, csr_out_dst,
                                               dinv_in, dinv_out, dbi, dbo,
                                               dwi + 16384, dwo + 16384, A, B, N);
    // S7: gather1 + chunked pool (A,B -> zb[:,0:128])
    gcn_pool8<<<cdiv(N, 32), 128, 0, stream>>>((const float4*)A, (const float4*)B,
                                               rp_in, deg_in, csr_in,
                                               rp_out, deg_out, csr_out_dst,
                                               dinv_in, dinv_out, dbi + 128, dbo + 128,
                                               batch, zb, N);
  } else {
    // fallback: R9/R10-proven schedule (3 buffers, dense pools)
    degi_kernel<<<degB, 256, 0, stream>>>(src, dst, deg_in, deg_out, E);
    dinv2_kernel<<<cdiv((long long)n2, 256), 256, 0, stream>>>(deg2, dinv2, n2);
    scan1<<<nb1, 256, 0, stream>>>(deg2, rpt, bsums, n2);
    scan2<<<1, 256, 0, stream>>>(bsums, boff, nb1);
    scan3<<<cdiv(n2, 256), 256, 0, stream>>>(rpt, boff, rp_in, cur_in, rp_out, cur_out, N, E, n2);
    cnt_sorted<<<cdiv(G, 256), 256, 0, stream>>>(batch, cnt, N, G);
    mm0_fill<<<mmB + fillB, 256, 0, stream>>>(x, dwi, dwo, B, C, N, mmB,
                                              src, dst, eattr, cur_in, cur_out,
                                              csr_in, csr_out_dst, E, fillB);
    gcn_gather4<<<cdiv(N, 4), 128, 0, stream>>>((const float4*)B, (const float4*)C,
                                                rp_in, deg_in, csr_in,
                                                rp_out, deg_out, csr_out_dst,
                                                dinv_in, dinv_out, dbi, dbo, (float4*)A, N);
    mm128d<<<mmB, 256, 0, stream>>>(A, dwi + 16384, dwo + 16384, B, C, N);
    gcn_gather4<<<cdiv(N, 4), 128, 0, stream>>>((const float4*)B, (const float4*)C,
                                                rp_in, deg_in, csr_in,
                                                rp_out, deg_out, csr_out_dst,
                                                dinv_in, dinv_out, dbi + 128, dbo + 128, (float4*)A, N);
    pool_kernel<<<cdiv(N, PCH), 128, 0, stream>>>(A, batch, zb, 0, N);
    mm128d<<<mmB, 256, 0, stream>>>(x, wl, wr, B, C, N);
    gat_fused2<<<cdiv(N, 4), 128, 0, stream>>>((const float4*)B, (const float4*)C,
                                               rp_in, deg_in, csr_in,
                                               we, att, gatb, (float4*)A, N);
    pool_kernel<<<cdiv(N, PCH), 128, 0, stream>>>(A, batch, zb, 128, N);
  }

  // head
  head_kernel<<<G, 128, 0, stream>>>(zb, cnt, w1, b1, w2, b2, (float*)d_out, G);
}